// Round 4
// baseline (1398.779 us; speedup 1.0000x reference)
//
#include <hip/hip_runtime.h>
#include <math.h>

#define NNODE 10000
#define NEDGE 160000
#define KNB   16
#define K1    17
#define NT    10
#define TN    10
#define DF    128
#define CAP   64
#define NPAIR (NNODE * NT)   /* 100000 (node,template) pairs */
#define NEG_BIG (-1e9f)

#define LOGQ2      (-3.32192809489f)   /* log2(0.1) */
#define KB_SCALE   (-14.4269504089f)   /* -10*log2e  */
#define CR_SCALE   (28.8539008178f)    /* +20*log2e  */
#define G_SCALE    (-0.069314718056f)  /* -ln2/10    */
#define LN2        0.69314718056f
#define TINYF      1e-30f

#if defined(__has_builtin)
#if __has_builtin(__builtin_amdgcn_exp2f)
#define EXP2F(x) __builtin_amdgcn_exp2f(x)
#endif
#if __has_builtin(__builtin_amdgcn_rcpf)
#define RCPF(x) __builtin_amdgcn_rcpf(x)
#endif
#endif
#ifndef EXP2F
#define EXP2F(x) __expf((x) * LN2)
#endif
#ifndef RCPF
#define RCPF(x) (1.0f / (x))
#endif
#define LOG2F(x) __log2f(x)

// Compiler-only barrier: DS ops from one wave execute IN ORDER in the LDS
// pipeline; compiler still emits lgkmcnt(N) before VALU consumes read data.
// All LDS traffic here is slot-private and slots never span waves.
#define CBAR() asm volatile("" ::: "memory")

// Packed fp32 (v_pk_{fma,mul,add}_f32) via ext_vector types.
typedef float f32x2 __attribute__((ext_vector_type(2)));
typedef float f32x4 __attribute__((ext_vector_type(4)));

__device__ __forceinline__ f32x2 mk2(float x, float y) { f32x2 r; r.x = x; r.y = y; return r; }
__device__ __forceinline__ f32x2 lo2(f32x4 v) { return __builtin_shufflevector(v, v, 0, 1); }
__device__ __forceinline__ f32x2 hi2(f32x4 v) { return __builtin_shufflevector(v, v, 2, 3); }
__device__ __forceinline__ f32x2 pk_add(f32x2 a, f32x2 b) { return a + b; }
__device__ __forceinline__ f32x2 pk_sub(f32x2 a, f32x2 b) { return a - b; }
__device__ __forceinline__ f32x2 pk_mul(f32x2 a, f32x2 b) { return a * b; }
__device__ __forceinline__ f32x2 pk_fma(f32x2 a, f32x2 b, f32x2 c) {
  return __builtin_elementwise_fma(a, b, c);
}
__device__ __forceinline__ f32x2 pk_max(f32x2 a, f32x2 b) {
  return mk2(fmaxf(a.x, b.x), fmaxf(a.y, b.y));
}
__device__ __forceinline__ f32x2 pk_exp2(f32x2 a) { return mk2(EXP2F(a.x), EXP2F(a.y)); }
__device__ __forceinline__ float clamp120(float x) { return fminf(120.f, fmaxf(-120.f, x)); }

// int64-vs-int32 sniff, computed by ONE lane and broadcast
__device__ __forceinline__ int detect_wide_wave(const int* ei) {
  int z = 0;
  if ((threadIdx.x & 63) == 0) {
#pragma unroll
    for (int i = 0; i < 32; ++i) z |= ei[2 * i + 1];
  }
  z = __shfl(z, 0, 64);
  return z == 0;
}

// ---------- fused: edge bucketing + feature dots (16-node tiles) + template stats ----------
__global__ void __launch_bounds__(256) k_prep(const int* __restrict__ ei,
                                              int* cnt, int* ebuf,
                                              const float* __restrict__ x,
                                              const float* __restrict__ tf,
                                              const float* __restrict__ tmpl,
                                              float* __restrict__ dots,
                                              float* __restrict__ nxv,
                                              float* __restrict__ nF2,
                                              float* __restrict__ Bq) {
  __shared__ float xs[16][DF];   // 8 KB
  const int tid = threadIdx.x;
  if (blockIdx.x < 625) {          // hist: 625*256 == NEDGE
    int wide = detect_wide_wave(ei);
    int e = blockIdx.x * 256 + tid;
    int s = wide ? ei[2 * e] : ei[e];
    int pos = atomicAdd(&cnt[s], 1);
    if (pos < CAP) ebuf[s * CAP + pos] = e;   // node-major: wave-coalesced select reads
    return;
  }
  const int db = blockIdx.x - 625;
  if (db == 0 && tid < NT * TN) {  // template stats, once
    const float* fp = tf + (size_t)tid * DF;
    float s = 0.f;
    for (int d = 0; d < DF; ++d) { float v = fp[d]; s += v * v; }
    nF2[tid] = s;
    const float* cp = tmpl + (size_t)tid * TN;
    float s2 = 0.f;
    for (int c = 0; c < TN; ++c) { float v = cp[c]; s2 += v * v; }
    Bq[tid] = 0.1f * s2;
  }
  const int nb = db * 16;
  const int nvalid = (NNODE - nb) < 16 ? (NNODE - nb) : 16;
  {
    const float4* xg = (const float4*)(x + (size_t)nb * DF);
    float4* xl = (float4*)&xs[0][0];
    for (int i = tid; i < nvalid * (DF / 4); i += 256) xl[i] = xg[i];
  }
  __syncthreads();
  for (int o = tid; o < nvalid * (NT * TN); o += 256) {
    int n = o / (NT * TN);
    int tb = o - n * (NT * TN);
    const float4* fp = (const float4*)(tf + (size_t)tb * DF);
    const float4* xp = (const float4*)&xs[n][0];
    float s = 0.f;
#pragma unroll
    for (int d = 0; d < DF / 4; ++d) {
      float4 a = xp[d], f = fp[d];
      s += a.x * f.x + a.y * f.y + a.z * f.z + a.w * f.w;
    }
    dots[(size_t)(nb + n) * (NT * TN) + tb] = s;
  }
  if (tid < nvalid) {
    const float4* xp = (const float4*)&xs[tid][0];
    float s = 0.f;
#pragma unroll
    for (int d = 0; d < DF / 4; ++d) {
      float4 a = xp[d];
      s += a.x * a.x + a.y * a.y + a.z * a.z + a.w * a.w;
    }
    nxv[nb + tid] = s;
  }
}

// ---------- wave-per-node: bitonic-sort 64 bucket entries, keep 16 smallest ----------
__global__ void __launch_bounds__(256) k_select(const int* __restrict__ ei,
                                                const int* __restrict__ cnt,
                                                const int* __restrict__ ebuf,
                                                int* __restrict__ nbrs,
                                                int* __restrict__ kcnt,
                                                int* __restrict__ Sg) {
  const int wv = threadIdx.x >> 6;
  const int lane = threadIdx.x & 63;
  const int i = blockIdx.x * 4 + wv;
  if (i >= NNODE) return;
  const int wide = detect_wide_wave(ei);
  int c = cnt[i]; c = c > CAP ? CAP : c;
  int v = (lane < c) ? ebuf[i * CAP + lane] : 0x7FFFFFFF;
#pragma unroll
  for (int k = 2; k <= 64; k <<= 1) {
#pragma unroll
    for (int j = k >> 1; j > 0; j >>= 1) {
      int pv = __shfl_xor(v, j, 64);
      bool up = ((lane & k) == 0);
      bool lower = ((lane & j) == 0);
      int mn = v < pv ? v : pv;
      int mx = v < pv ? pv : v;
      v = (lower == up) ? mn : mx;
    }
  }
  const int m = c < KNB ? c : KNB;
  if (lane == 0) { kcnt[i] = m; Sg[i * K1] = i; }
  if (lane < KNB) {
    int d = 0;
    if (lane < m) d = wide ? ei[2 * (NEDGE + v)] : ei[NEDGE + v];
    nbrs[i * KNB + lane] = d;
    Sg[i * K1 + 1 + lane] = d;
  }
}

// ---------- C1 bitmasks: one thread per (node, row) ----------
__global__ void __launch_bounds__(256) k_c1b(const int* __restrict__ nbrs,
                                             const int* __restrict__ kcnt,
                                             const int* __restrict__ Sg,
                                             unsigned int* __restrict__ bitsG,
                                             float* __restrict__ Ag) {
  int idx = blockIdx.x * 256 + threadIdx.x;
  if (idx >= NNODE * K1) return;
  int i = idx / K1;
  int a = idx - i * K1;
  int kc = kcnt[i];
  unsigned int vmask = (kc >= KNB) ? 0x1FFFFu : ((2u << kc) - 1u);
  unsigned int bits = 0;
  bool va = (a == 0) || (a - 1 < kc);
  if (va) {
    int S[K1];
#pragma unroll
    for (int b = 0; b < K1; ++b) S[b] = Sg[i * K1 + b];
    int u = S[a];
    int ku = kcnt[u];
    const int* np = nbrs + (size_t)u * KNB;
    for (int j = 0; j < ku; ++j) {
      int w = np[j];
#pragma unroll
      for (int b = 0; b < K1; ++b) bits |= (S[b] == w) ? (1u << b) : 0u;
    }
    bits &= vmask;
  }
  bitsG[idx] = bits;
  Ag[idx] = (float)__popc(bits) / (float)(1 + kc);
}

// ---------- FGW main: flat pair list, TWO pairs per 10-lane slot (ILP x2) ----------
// Block = 128 threads = 2 waves; wave = 6 real slots (lanes 0-59) + 1 dummy
// (lanes 60-63).  Each slot processes pairs (2q, 2q+1): two independent
// dependency chains per wave cover LDS round-trip latency; staging writes and
// the u/w exchange are shared (combined b128/b64 ops whose .xy/.zw halves
// belong to pair A/B — free via register-pair aliasing).
// Per-slot LDS (stride 412 dwords, base ≡ 28s mod 32 → b128 broadcast reads
// conflict-free):
//   KT rows: row a: A at [24a .. 24a+9], B at [24a+12 .. 24a+21]  (a=0..16)
//   overlays (KT dead during log/stab/mult):
//     u  combined [0..39]    : f32x4 at [4b] = (uA_b, uA_{10+b}, uB_b, uB_{10+b})
//     g  per-pp   [44+12pp+b]
//     w  combined [68+2b]    = (wA_b, wB_b)
//     f  per-pp   [88+20pp]  : fr0 at +b, fr1 at +10+b
//     acc per-pp  [128+10pp+b]
// Per-node tables (Sg/nxv/dots/Ag/bitsG) are RELOADED from global each k-step
// (L2-hot, VMEM pipe idle) instead of held in VGPRs — register diet.
#define SLOT_STRIDE 412

__global__ void __launch_bounds__(128, 2) k_main(
    const float* __restrict__ tmpl,
    const int* __restrict__ kcnt, const int* __restrict__ Sg,
    const unsigned int* __restrict__ bitsG, const float* __restrict__ Ag,
    const float* __restrict__ dots, const float* __restrict__ nxv,
    const float* __restrict__ nF2, const float* __restrict__ Bq,
    float* __restrict__ out)
{
  __shared__ float SH[2 * 7 * SLOT_STRIDE + 72];  // junk-read pad (rows 17..19)

  const int wv = threadIdx.x >> 6;
  const int lane = threadIdx.x & 63;
  const int p0 = lane / 10;              // 0..6 (6 = dummy slot, lanes 60-63)
  const int b = lane - p0 * 10;          // 0..9
  const int base2 = (blockIdx.x * 12 + wv * 6 + p0) * 2;
  const bool act = (p0 < 6) && (base2 < NPAIR);

  float* const KTp = &SH[(wv * 7 + p0) * SLOT_STRIDE];

  int   nodeV[2], tIv[2], tbV[2], kcV[2];
  float lp_r0[2], lp_r1[2], BbV[2], nf2V[2];
  f32x2 c2v[2][5];
  f32x2 Tp2[2][10];

#pragma unroll
  for (int pp = 0; pp < 2; ++pp) {
    const int pair = act ? (base2 + pp) : 0;   // clamp: no OOB global reads
    const int node = pair / 10;
    const int tI = pair - node * 10;
    const int tb = tI * TN + b;
    nodeV[pp] = node; tIv[pp] = tI; tbV[pp] = tb;
    const int kc = kcnt[node];
    kcV[pp] = kc;
    const float cnt1 = (float)(1 + kc);
    const float inv_cnt1 = 1.f / cnt1;
    const float logp2v = -LOG2F(cnt1);
    lp_r0[pp] = ((b == 0) || (b - 1 < kc)) ? logp2v : NEG_BIG;
    lp_r1[pp] = ((9 + b) < kc) ? logp2v : NEG_BIG;
    const f32x2* cp = (const f32x2*)(tmpl + (size_t)tb * TN);
#pragma unroll
    for (int j = 0; j < 5; ++j) c2v[pp][j] = cp[j];
    BbV[pp] = Bq[tb];
    nf2V[pp] = nF2[tb];
#pragma unroll
    for (int j = 0; j < 10; ++j) Tp2[pp][j] = mk2(0.f, 0.f);
#pragma unroll
    for (int a = 0; a < K1; ++a) {
      bool va = (a == 0) || (a - 1 < kc);
      float tv = va ? (inv_cnt1 * 0.1f) : 0.f;
      if (a < 10) Tp2[pp][a].x = tv; else Tp2[pp][a - 10].y = tv;
    }
  }

#pragma unroll 1
  for (int k = 0; k < 6; ++k) {
    CBAR();
    // ---- stage Tp into KT (row-major, A|B halves) ----
#pragma unroll
    for (int pp = 0; pp < 2; ++pp) {
      float* kt = KTp + pp * 12;
#pragma unroll
      for (int a = 0; a < K1; ++a)
        kt[a * 24 + b] = (a < 10) ? Tp2[pp][a].x : Tp2[pp][a - 10].y;
    }
    CBAR();
    // ---- R = Tp @ C2^T ----
    float R[2][K1];
#pragma unroll
    for (int pp = 0; pp < 2; ++pp) {
#pragma unroll
      for (int c = 0; c < K1; ++c) {
        const float* row = &KTp[c * 24 + pp * 12];
        f32x4 u0 = *(const f32x4*)row;
        f32x4 u1 = *(const f32x4*)(row + 4);
        f32x2 u2 = *(const f32x2*)(row + 8);
        f32x2 aA = pk_mul(lo2(u0), c2v[pp][0]);
        aA = pk_fma(hi2(u0), c2v[pp][1], aA);
        f32x2 aB = pk_mul(lo2(u1), c2v[pp][2]);
        aB = pk_fma(hi2(u1), c2v[pp][3], aB);
        aA = pk_fma(u2, c2v[pp][4], aA);
        aA = pk_add(aA, aB);
        R[pp][c] = aA.x + aA.y;
      }
    }
    // ---- cross = C1 @ R (bitmasks reloaded) + base (tables reloaded) → logK ----
    f32x2 Kc2v[2][8]; float k16[2];
#pragma unroll
    for (int pp = 0; pp < 2; ++pp) {
      const int node = nodeV[pp]; const int tb = tbV[pp]; const int kc = kcV[pp];
      const int* sgp = &Sg[node * K1];
      const unsigned int* bp = &bitsG[node * K1];
      const float* agp = &Ag[node * K1];
#pragma unroll
      for (int a = 0; a < K1; ++a) {
        bool va = (a == 0) || (a - 1 < kc);
        int sa = sgp[a];
        float Ma = (va ? (nxv[sa] - 2.f * dots[(size_t)sa * (NT * TN) + tb]) : 0.f) + nf2V[pp];
        float basev = 0.5f * Ma + agp[a] + BbV[pp];
        unsigned int m = bp[a];
        float cr = 0.f;
        if (m) {
#pragma unroll
          for (int c = 0; c < K1; ++c)
            if (m & (1u << c)) cr += R[pp][c];
        }
        float val = KB_SCALE * basev + CR_SCALE * cr;
        if (a == 16) k16[pp] = val;
        else if (a & 1) Kc2v[pp][a >> 1].y = val;
        else Kc2v[pp][a >> 1].x = val;
      }
    }

    if (k == 5) {  // final distance
#pragma unroll
      for (int pp = 0; pp < 2; ++pp) {
        const int node = nodeV[pp]; const int tb = tbV[pp]; const int kc = kcV[pp];
        const int* sgp = &Sg[node * K1];
        float acc = 0.f;
#pragma unroll
        for (int a = 0; a < K1; ++a) {
          bool va = (a == 0) || (a - 1 < kc);
          int sa = sgp[a];
          float Ma = (va ? (nxv[sa] - 2.f * dots[(size_t)sa * (NT * TN) + tb]) : 0.f) + nf2V[pp];
          float kcv = (a == 16) ? k16[pp] : ((a & 1) ? Kc2v[pp][a >> 1].y : Kc2v[pp][a >> 1].x);
          float tpv = (a < 10) ? Tp2[pp][a].x : Tp2[pp][a - 10].y;
          acc += tpv * (0.25f * Ma + 0.5f * (G_SCALE * kcv));
        }
        KTp[128 + 10 * pp + b] = acc;
      }
      CBAR();
      if (act && b < 2) {
        const float* ap = &KTp[128 + 10 * b];
        float s = 0.f;
#pragma unroll
        for (int j = 0; j < TN; ++j) s += ap[j];
        int nodeS = b ? nodeV[1] : nodeV[0];
        int tIS = b ? tIv[1] : tIv[0];
        out[nodeS * NT + tIS] = s;
      }
      return;
    }

    // ---- stage logK, read back rows b and 10+b ----
    CBAR();
#pragma unroll
    for (int pp = 0; pp < 2; ++pp) {
      float* kt = KTp + pp * 12;
#pragma unroll
      for (int a = 0; a < 16; ++a) kt[a * 24 + b] = (a & 1) ? Kc2v[pp][a >> 1].y : Kc2v[pp][a >> 1].x;
      kt[16 * 24 + b] = k16[pp];
    }
    CBAR();
    f32x2 Kr0v[2][5], Kr1v[2][5];
#pragma unroll
    for (int pp = 0; pp < 2; ++pp) {
      const float* r0 = &KTp[b * 24 + pp * 12];
      f32x4 u0 = *(const f32x4*)r0;
      f32x4 u1 = *(const f32x4*)(r0 + 4);
      f32x2 u2 = *(const f32x2*)(r0 + 8);
      Kr0v[pp][0] = lo2(u0); Kr0v[pp][1] = hi2(u0);
      Kr0v[pp][2] = lo2(u1); Kr0v[pp][3] = hi2(u1);
      Kr0v[pp][4] = u2;
      // b>=7: rows 17..19 read in-bounds junk (pad / next slot); those rows'
      // u is forced to 0 via P01 below, so junk never reaches real columns.
      const float* r1 = &KTp[(10 + b) * 24 + pp * 12];
      f32x4 w0 = *(const f32x4*)r1;
      f32x4 w1 = *(const f32x4*)(r1 + 4);
      f32x2 w2 = *(const f32x2*)(r1 + 8);
      Kr1v[pp][0] = lo2(w0); Kr1v[pp][1] = hi2(w0);
      Kr1v[pp][2] = lo2(w1); Kr1v[pp][3] = hi2(w1);
      Kr1v[pp][4] = w2;
    }

    // ---- Sinkhorn iters 1-2 in log domain ----
    f32x2 gr[2][5];
    float g2v[2], fr0v[2], fr1v[2];
#pragma unroll 1
    for (int it = 0; it < 2; ++it) {
#pragma unroll
      for (int pp = 0; pp < 2; ++pp) {
        f32x2 v[8]; float v16;
        if (it == 0) {
#pragma unroll
          for (int i = 0; i < 8; ++i) v[i] = Kc2v[pp][i];
          v16 = k16[pp];
        } else {
          const float* fb = &KTp[88 + pp * 20];
          f32x4 f0 = *(const f32x4*)fb;
          f32x4 f1 = *(const f32x4*)(fb + 4);
          f32x4 f2 = *(const f32x4*)(fb + 8);
          f32x4 f3 = *(const f32x4*)(fb + 12);
          float fx = fb[16];
          v[0] = pk_add(Kc2v[pp][0], lo2(f0));
          v[1] = pk_add(Kc2v[pp][1], hi2(f0));
          v[2] = pk_add(Kc2v[pp][2], lo2(f1));
          v[3] = pk_add(Kc2v[pp][3], hi2(f1));
          v[4] = pk_add(Kc2v[pp][4], lo2(f2));
          v[5] = pk_add(Kc2v[pp][5], hi2(f2));
          v[6] = pk_add(Kc2v[pp][6], lo2(f3));
          v[7] = pk_add(Kc2v[pp][7], hi2(f3));
          v16 = k16[pp] + fx;
        }
        f32x2 m01 = pk_max(pk_max(v[0], v[1]), pk_max(v[2], v[3]));
        f32x2 m23 = pk_max(pk_max(v[4], v[5]), pk_max(v[6], v[7]));
        f32x2 mm = pk_max(m01, m23);
        float mx = fmaxf(fmaxf(mm.x, mm.y), v16);
        f32x2 mxb = mk2(mx, mx);
        f32x2 ssA = pk_exp2(pk_sub(v[0], mxb));
        ssA = pk_add(ssA, pk_exp2(pk_sub(v[1], mxb)));
        ssA = pk_add(ssA, pk_exp2(pk_sub(v[2], mxb)));
        ssA = pk_add(ssA, pk_exp2(pk_sub(v[3], mxb)));
        f32x2 ssB = pk_exp2(pk_sub(v[4], mxb));
        ssB = pk_add(ssB, pk_exp2(pk_sub(v[5], mxb)));
        ssB = pk_add(ssB, pk_exp2(pk_sub(v[6], mxb)));
        ssB = pk_add(ssB, pk_exp2(pk_sub(v[7], mxb)));
        f32x2 ss = pk_add(ssA, ssB);
        float s = ss.x + ss.y + EXP2F(v16 - mx);
        g2v[pp] = LOGQ2 - mx - LOG2F(s);
        KTp[44 + pp * 12 + b] = g2v[pp];
      }
      CBAR();
#pragma unroll
      for (int pp = 0; pp < 2; ++pp) {
        const float* gb = &KTp[44 + pp * 12];
        f32x4 g0 = *(const f32x4*)gb;
        f32x4 g1 = *(const f32x4*)(gb + 4);
        f32x2 gx = *(const f32x2*)(gb + 8);
        gr[pp][0] = lo2(g0); gr[pp][1] = hi2(g0);
        gr[pp][2] = lo2(g1); gr[pp][3] = hi2(g1);
        gr[pp][4] = gx;
        f32x2 w0[5], w1[5];
#pragma unroll
        for (int j = 0; j < 5; ++j) w0[j] = pk_add(Kr0v[pp][j], gr[pp][j]);
#pragma unroll
        for (int j = 0; j < 5; ++j) w1[j] = pk_add(Kr1v[pp][j], gr[pp][j]);
        f32x2 a01 = pk_max(pk_max(w0[0], w0[1]), pk_max(w0[2], w0[3]));
        a01 = pk_max(a01, w0[4]);
        float mxa = fmaxf(a01.x, a01.y);
        f32x2 b01 = pk_max(pk_max(w1[0], w1[1]), pk_max(w1[2], w1[3]));
        b01 = pk_max(b01, w1[4]);
        float mxb2 = fmaxf(b01.x, b01.y);
        f32x2 mab = mk2(mxa, mxa);
        f32x2 mbb = mk2(mxb2, mxb2);
        f32x2 sx = pk_exp2(pk_sub(w0[0], mab));
        sx = pk_add(sx, pk_exp2(pk_sub(w0[1], mab)));
        sx = pk_add(sx, pk_exp2(pk_sub(w0[2], mab)));
        sx = pk_add(sx, pk_exp2(pk_sub(w0[3], mab)));
        sx = pk_add(sx, pk_exp2(pk_sub(w0[4], mab)));
        f32x2 sy = pk_exp2(pk_sub(w1[0], mbb));
        sy = pk_add(sy, pk_exp2(pk_sub(w1[1], mbb)));
        sy = pk_add(sy, pk_exp2(pk_sub(w1[2], mbb)));
        sy = pk_add(sy, pk_exp2(pk_sub(w1[3], mbb)));
        sy = pk_add(sy, pk_exp2(pk_sub(w1[4], mbb)));
        fr0v[pp] = lp_r0[pp] - mxa - LOG2F(sx.x + sx.y);
        fr1v[pp] = lp_r1[pp] - mxb2 - LOG2F(sy.x + sy.y);
        KTp[88 + pp * 20 + b] = fr0v[pp];
        KTp[88 + pp * 20 + 10 + b] = fr1v[pp];   // b>=7 -> pad slots, never consumed
      }
      CBAR();
    }

    // ---- stabilized kernels from (f2, g2) snapshot ----
    f32x2 Kcs2[2][10];
    f32x2 Krs01[2][10];
    float P00[2], P01[2], Q0[2];
#pragma unroll
    for (int pp = 0; pp < 2; ++pp) {
      const float* fb = &KTp[88 + pp * 20];
      f32x4 F0 = *(const f32x4*)fb;
      f32x4 F1 = *(const f32x4*)(fb + 4);
      f32x4 F2 = *(const f32x4*)(fb + 8);
      f32x4 F3 = *(const f32x4*)(fb + 12);
      float f16v = fb[16];
      float fs[K1];
      fs[0] = F0.x; fs[1] = F0.y; fs[2] = F0.z; fs[3] = F0.w;
      fs[4] = F1.x; fs[5] = F1.y; fs[6] = F1.z; fs[7] = F1.w;
      fs[8] = F2.x; fs[9] = F2.y; fs[10] = F2.z; fs[11] = F2.w;
      fs[12] = F3.x; fs[13] = F3.y; fs[14] = F3.z; fs[15] = F3.w;
      fs[16] = f16v;
      float qs[K1];
#pragma unroll
      for (int a = 0; a < K1; ++a) {
        float kcv = (a == 16) ? k16[pp] : ((a & 1) ? Kc2v[pp][a >> 1].y : Kc2v[pp][a >> 1].x);
        qs[a] = kcv + fs[a];
      }
      float sigma = qs[0];
#pragma unroll
      for (int a = 1; a < K1; ++a) sigma = fmaxf(sigma, qs[a]);
#pragma unroll
      for (int j = 0; j < 10; ++j) {
        float kx = EXP2F(qs[j] - sigma);
        float ky = (j < 7) ? EXP2F(qs[10 + j] - sigma) : 0.f;
        Kcs2[pp][j] = mk2(kx, ky);
      }
      Q0[pp] = EXP2F(clamp120(LOGQ2 - sigma - g2v[pp]));
      f32x2 a0[5], a1[5];
#pragma unroll
      for (int j = 0; j < 5; ++j) a0[j] = pk_add(Kr0v[pp][j], gr[pp][j]);
#pragma unroll
      for (int j = 0; j < 5; ++j) a1[j] = pk_add(Kr1v[pp][j], gr[pp][j]);
      f32x2 r0m = pk_max(pk_max(a0[0], a0[1]), pk_max(a0[2], a0[3]));
      r0m = pk_max(r0m, a0[4]);
      float rho0 = fmaxf(r0m.x, r0m.y);
      f32x2 r1m = pk_max(pk_max(a1[0], a1[1]), pk_max(a1[2], a1[3]));
      r1m = pk_max(r1m, a1[4]);
      float rho1 = fmaxf(r1m.x, r1m.y);
#pragma unroll
      for (int j = 0; j < 5; ++j) {
        Krs01[pp][2 * j]     = mk2(EXP2F(a0[j].x - rho0), EXP2F(a1[j].x - rho1));
        Krs01[pp][2 * j + 1] = mk2(EXP2F(a0[j].y - rho0), EXP2F(a1[j].y - rho1));
      }
      P00[pp] = EXP2F(clamp120((lp_r0[pp] - rho0) - fr0v[pp]));
      // pad rows (17..19): force u==0 so junk can never poison real columns.
      P01[pp] = (b < 7) ? EXP2F(clamp120((lp_r1[pp] - rho1) - fr1v[pp])) : 0.f;
    }

    // ---- Sinkhorn iters 3..20: multiplicative, combined u/w exchange ----
    float Slast[2], t0v[2], t1v[2];
    {  // peeled iter 3: u == 1
      float wb2[2];
#pragma unroll
      for (int pp = 0; pp < 2; ++pp) {
        f32x2 SA = pk_add(pk_add(Kcs2[pp][0], Kcs2[pp][1]), pk_add(Kcs2[pp][2], Kcs2[pp][3]));
        f32x2 SB = pk_add(pk_add(Kcs2[pp][4], Kcs2[pp][5]), pk_add(Kcs2[pp][6], Kcs2[pp][7]));
        f32x2 S2 = pk_add(pk_add(SA, SB), pk_add(Kcs2[pp][8], Kcs2[pp][9]));
        float S = fmaxf(S2.x + S2.y, TINYF);
        Slast[pp] = S;
        wb2[pp] = Q0[pp] * RCPF(S);
      }
      *(f32x2*)&KTp[68 + 2 * b] = mk2(wb2[0], wb2[1]);
      CBAR();
      f32x4 Wq[5];
#pragma unroll
      for (int i = 0; i < 5; ++i) Wq[i] = *(const f32x4*)&KTp[68 + 4 * i];
#pragma unroll
      for (int pp = 0; pp < 2; ++pp) {
        float w0 = pp ? Wq[0].y : Wq[0].x, w1 = pp ? Wq[0].w : Wq[0].z;
        float w2 = pp ? Wq[1].y : Wq[1].x, w3 = pp ? Wq[1].w : Wq[1].z;
        float w4 = pp ? Wq[2].y : Wq[2].x, w5 = pp ? Wq[2].w : Wq[2].z;
        float w6 = pp ? Wq[3].y : Wq[3].x, w7 = pp ? Wq[3].w : Wq[3].z;
        float w8 = pp ? Wq[4].y : Wq[4].x, w9 = pp ? Wq[4].w : Wq[4].z;
        f32x2 tA = pk_mul(Krs01[pp][0], mk2(w0, w0));
        tA = pk_fma(Krs01[pp][1], mk2(w1, w1), tA);
        tA = pk_fma(Krs01[pp][2], mk2(w2, w2), tA);
        tA = pk_fma(Krs01[pp][3], mk2(w3, w3), tA);
        tA = pk_fma(Krs01[pp][4], mk2(w4, w4), tA);
        f32x2 tB = pk_mul(Krs01[pp][5], mk2(w5, w5));
        tB = pk_fma(Krs01[pp][6], mk2(w6, w6), tB);
        tB = pk_fma(Krs01[pp][7], mk2(w7, w7), tB);
        tB = pk_fma(Krs01[pp][8], mk2(w8, w8), tB);
        tB = pk_fma(Krs01[pp][9], mk2(w9, w9), tB);
        f32x2 t01 = pk_add(tA, tB);
        t0v[pp] = t01.x; t1v[pp] = t01.y;
      }
    }
#pragma unroll 1
    for (int it = 0; it < 17; ++it) {   // iters 4..20
      float u0A = P00[0] * RCPF(fmaxf(t0v[0], TINYF));
      float u1A = P01[0] * RCPF(fmaxf(t1v[0], TINYF));
      float u0B = P00[1] * RCPF(fmaxf(t0v[1], TINYF));
      float u1B = P01[1] * RCPF(fmaxf(t1v[1], TINYF));
      f32x4 uw; uw.x = u0A; uw.y = u1A; uw.z = u0B; uw.w = u1B;
      *(f32x4*)&KTp[4 * b] = uw;       // ONE b128 write for both pairs
      CBAR();
      f32x2 SA0 = mk2(0.f, 0.f), SB0 = mk2(0.f, 0.f);
      f32x2 SA1 = mk2(0.f, 0.f), SB1 = mk2(0.f, 0.f);
#pragma unroll
      for (int j = 0; j < 10; ++j) {
        f32x4 U = *(const f32x4*)&KTp[4 * j];
        if (j < 5) { SA0 = pk_fma(Kcs2[0][j], lo2(U), SA0); SA1 = pk_fma(Kcs2[1][j], hi2(U), SA1); }
        else       { SB0 = pk_fma(Kcs2[0][j], lo2(U), SB0); SB1 = pk_fma(Kcs2[1][j], hi2(U), SB1); }
      }
      float wb2[2];
      {
        f32x2 S20 = pk_add(SA0, SB0);
        float S0 = fmaxf(S20.x + S20.y, TINYF);
        Slast[0] = S0; wb2[0] = Q0[0] * RCPF(S0);
        f32x2 S21 = pk_add(SA1, SB1);
        float S1 = fmaxf(S21.x + S21.y, TINYF);
        Slast[1] = S1; wb2[1] = Q0[1] * RCPF(S1);
      }
      *(f32x2*)&KTp[68 + 2 * b] = mk2(wb2[0], wb2[1]);
      CBAR();
      f32x4 Wq[5];
#pragma unroll
      for (int i = 0; i < 5; ++i) Wq[i] = *(const f32x4*)&KTp[68 + 4 * i];
#pragma unroll
      for (int pp = 0; pp < 2; ++pp) {
        float w0 = pp ? Wq[0].y : Wq[0].x, w1 = pp ? Wq[0].w : Wq[0].z;
        float w2 = pp ? Wq[1].y : Wq[1].x, w3 = pp ? Wq[1].w : Wq[1].z;
        float w4 = pp ? Wq[2].y : Wq[2].x, w5 = pp ? Wq[2].w : Wq[2].z;
        float w6 = pp ? Wq[3].y : Wq[3].x, w7 = pp ? Wq[3].w : Wq[3].z;
        float w8 = pp ? Wq[4].y : Wq[4].x, w9 = pp ? Wq[4].w : Wq[4].z;
        f32x2 tA = pk_mul(Krs01[pp][0], mk2(w0, w0));
        tA = pk_fma(Krs01[pp][1], mk2(w1, w1), tA);
        tA = pk_fma(Krs01[pp][2], mk2(w2, w2), tA);
        tA = pk_fma(Krs01[pp][3], mk2(w3, w3), tA);
        tA = pk_fma(Krs01[pp][4], mk2(w4, w4), tA);
        f32x2 tB = pk_mul(Krs01[pp][5], mk2(w5, w5));
        tB = pk_fma(Krs01[pp][6], mk2(w6, w6), tB);
        tB = pk_fma(Krs01[pp][7], mk2(w7, w7), tB);
        tB = pk_fma(Krs01[pp][8], mk2(w8, w8), tB);
        tB = pk_fma(Krs01[pp][9], mk2(w9, w9), tB);
        f32x2 t01 = pk_add(tA, tB);
        t0v[pp] = t01.x; t1v[pp] = t01.y;
      }
    }

    // ---- final u + FW transport update: Tn = u * Kcs * (0.1/Slast) ----
    {
      float u0A = P00[0] * RCPF(fmaxf(t0v[0], TINYF));
      float u1A = P01[0] * RCPF(fmaxf(t1v[0], TINYF));
      float u0B = P00[1] * RCPF(fmaxf(t0v[1], TINYF));
      float u1B = P01[1] * RCPF(fmaxf(t1v[1], TINYF));
      f32x4 uw; uw.x = u0A; uw.y = u1A; uw.z = u0B; uw.w = u1B;
      *(f32x4*)&KTp[4 * b] = uw;
      CBAR();
      const float gam = 2.f / ((float)k + 2.f);
      const float om = 1.f - gam;
      const f32x2 omb = mk2(om, om);
      const float gs0 = gam * 0.1f * RCPF(Slast[0]);
      const float gs1 = gam * 0.1f * RCPF(Slast[1]);
      const f32x2 gsb0 = mk2(gs0, gs0);
      const f32x2 gsb1 = mk2(gs1, gs1);
#pragma unroll
      for (int j = 0; j < 10; ++j) {
        f32x4 U = *(const f32x4*)&KTp[4 * j];
        Tp2[0][j] = pk_fma(omb, Tp2[0][j], pk_mul(gsb0, pk_mul(Kcs2[0][j], lo2(U))));
        Tp2[1][j] = pk_fma(omb, Tp2[1][j], pk_mul(gsb1, pk_mul(Kcs2[1][j], hi2(U))));
      }
    }
  }
}

extern "C" void kernel_launch(void* const* d_in, const int* in_sizes, int n_in,
                              void* d_out, int out_size, void* d_ws, size_t ws_size,
                              hipStream_t stream) {
  const float* x    = (const float*)d_in[0];
  const int*   ei   = (const int*)d_in[1];
  const float* tmpl = (const float*)d_in[2];
  const float* tf   = (const float*)d_in[3];
  float* out = (float*)d_out;

  int* cnt  = (int*)d_ws;
  int* ebuf = cnt + NNODE;
  int* nbrs = ebuf + (size_t)NNODE * CAP;
  int* kcnt = nbrs + (size_t)NNODE * KNB;
  int* Sg   = kcnt + NNODE;
  unsigned int* bits = (unsigned int*)(Sg + (size_t)NNODE * K1);
  float* Ag   = (float*)(bits + (size_t)NNODE * K1);
  float* dots = Ag + (size_t)NNODE * K1;
  float* nxv  = dots + (size_t)NNODE * (NT * TN);
  float* nF2  = nxv + NNODE;
  float* Bq   = nF2 + NT * TN;

  hipMemsetAsync(cnt, 0, NNODE * sizeof(int), stream);
  k_prep<<<625 + (NNODE + 15) / 16, 256, 0, stream>>>(ei, cnt, ebuf, x, tf, tmpl,
                                                      dots, nxv, nF2, Bq);
  k_select<<<(NNODE + 3) / 4, 256, 0, stream>>>(ei, cnt, ebuf, nbrs, kcnt, Sg);
  k_c1b<<<(NNODE * K1 + 255) / 256, 256, 0, stream>>>(nbrs, kcnt, Sg, bits, Ag);
  k_main<<<(NPAIR + 23) / 24, 128, 0, stream>>>(tmpl, kcnt, Sg, bits, Ag, dots, nxv, nF2, Bq, out);
}

// Round 5
// 831.430 us; speedup vs baseline: 1.6824x; 1.6824x over previous
//
#include <hip/hip_runtime.h>
#include <math.h>

#define NNODE 10000
#define NEDGE 160000
#define KNB   16
#define K1    17
#define NT    10
#define TN    10
#define DF    128
#define CAP   64
#define NPAIR (NNODE * NT)   /* 100000 (node,template) pairs */
#define NEG_BIG (-1e9f)

#define LOGQ2      (-3.32192809489f)   /* log2(0.1) */
#define KB_SCALE   (-14.4269504089f)   /* -10*log2e  */
#define CR_SCALE   (28.8539008178f)    /* +20*log2e  */
#define G_SCALE    (-0.069314718056f)  /* -ln2/10    */
#define LN2        0.69314718056f
#define TINYF      1e-30f

#if defined(__has_builtin)
#if __has_builtin(__builtin_amdgcn_exp2f)
#define EXP2F(x) __builtin_amdgcn_exp2f(x)
#endif
#if __has_builtin(__builtin_amdgcn_rcpf)
#define RCPF(x) __builtin_amdgcn_rcpf(x)
#endif
#endif
#ifndef EXP2F
#define EXP2F(x) __expf((x) * LN2)
#endif
#ifndef RCPF
#define RCPF(x) (1.0f / (x))
#endif
#define LOG2F(x) __log2f(x)

// Compiler-only barrier: DS ops from one wave execute IN ORDER in the LDS
// pipeline; compiler still emits lgkmcnt(N) before VALU consumes read data.
// All LDS traffic here is slot-private and slots never span waves.
#define CBAR() asm volatile("" ::: "memory")

// Packed fp32 (v_pk_{fma,mul,add}_f32) via ext_vector types.
typedef float f32x2 __attribute__((ext_vector_type(2)));
typedef float f32x4 __attribute__((ext_vector_type(4)));

__device__ __forceinline__ f32x2 mk2(float x, float y) { f32x2 r; r.x = x; r.y = y; return r; }
__device__ __forceinline__ f32x2 lo2(f32x4 v) { return __builtin_shufflevector(v, v, 0, 1); }
__device__ __forceinline__ f32x2 hi2(f32x4 v) { return __builtin_shufflevector(v, v, 2, 3); }
__device__ __forceinline__ f32x2 pk_add(f32x2 a, f32x2 b) { return a + b; }
__device__ __forceinline__ f32x2 pk_sub(f32x2 a, f32x2 b) { return a - b; }
__device__ __forceinline__ f32x2 pk_mul(f32x2 a, f32x2 b) { return a * b; }
__device__ __forceinline__ f32x2 pk_fma(f32x2 a, f32x2 b, f32x2 c) {
  return __builtin_elementwise_fma(a, b, c);
}
__device__ __forceinline__ f32x2 pk_max(f32x2 a, f32x2 b) {
  return mk2(fmaxf(a.x, b.x), fmaxf(a.y, b.y));
}
__device__ __forceinline__ f32x2 pk_exp2(f32x2 a) { return mk2(EXP2F(a.x), EXP2F(a.y)); }
__device__ __forceinline__ float clamp120(float x) { return fminf(120.f, fmaxf(-120.f, x)); }

// int64-vs-int32 sniff, computed by ONE lane and broadcast
__device__ __forceinline__ int detect_wide_wave(const int* ei) {
  int z = 0;
  if ((threadIdx.x & 63) == 0) {
#pragma unroll
    for (int i = 0; i < 32; ++i) z |= ei[2 * i + 1];
  }
  z = __shfl(z, 0, 64);
  return z == 0;
}

// ---------- fused: edge bucketing + feature dots (16-node tiles) + template stats ----------
__global__ void __launch_bounds__(256) k_prep(const int* __restrict__ ei,
                                              int* cnt, int* ebuf,
                                              const float* __restrict__ x,
                                              const float* __restrict__ tf,
                                              const float* __restrict__ tmpl,
                                              float* __restrict__ dots,
                                              float* __restrict__ nxv,
                                              float* __restrict__ nF2,
                                              float* __restrict__ Bq) {
  __shared__ float xs[16][DF];   // 8 KB
  const int tid = threadIdx.x;
  if (blockIdx.x < 625) {          // hist: 625*256 == NEDGE
    int wide = detect_wide_wave(ei);
    int e = blockIdx.x * 256 + tid;
    int s = wide ? ei[2 * e] : ei[e];
    int pos = atomicAdd(&cnt[s], 1);
    if (pos < CAP) ebuf[s * CAP + pos] = e;   // node-major: wave-coalesced select reads
    return;
  }
  const int db = blockIdx.x - 625;
  if (db == 0 && tid < NT * TN) {  // template stats, once
    const float* fp = tf + (size_t)tid * DF;
    float s = 0.f;
    for (int d = 0; d < DF; ++d) { float v = fp[d]; s += v * v; }
    nF2[tid] = s;
    const float* cp = tmpl + (size_t)tid * TN;
    float s2 = 0.f;
    for (int c = 0; c < TN; ++c) { float v = cp[c]; s2 += v * v; }
    Bq[tid] = 0.1f * s2;
  }
  const int nb = db * 16;
  const int nvalid = (NNODE - nb) < 16 ? (NNODE - nb) : 16;
  {
    const float4* xg = (const float4*)(x + (size_t)nb * DF);
    float4* xl = (float4*)&xs[0][0];
    for (int i = tid; i < nvalid * (DF / 4); i += 256) xl[i] = xg[i];
  }
  __syncthreads();
  for (int o = tid; o < nvalid * (NT * TN); o += 256) {
    int n = o / (NT * TN);
    int tb = o - n * (NT * TN);
    const float4* fp = (const float4*)(tf + (size_t)tb * DF);
    const float4* xp = (const float4*)&xs[n][0];
    float s = 0.f;
#pragma unroll
    for (int d = 0; d < DF / 4; ++d) {
      float4 a = xp[d], f = fp[d];
      s += a.x * f.x + a.y * f.y + a.z * f.z + a.w * f.w;
    }
    dots[(size_t)(nb + n) * (NT * TN) + tb] = s;
  }
  if (tid < nvalid) {
    const float4* xp = (const float4*)&xs[tid][0];
    float s = 0.f;
#pragma unroll
    for (int d = 0; d < DF / 4; ++d) {
      float4 a = xp[d];
      s += a.x * a.x + a.y * a.y + a.z * a.z + a.w * a.w;
    }
    nxv[nb + tid] = s;
  }
}

// ---------- wave-per-node: bitonic-sort 64 bucket entries, keep 16 smallest ----------
__global__ void __launch_bounds__(256) k_select(const int* __restrict__ ei,
                                                const int* __restrict__ cnt,
                                                const int* __restrict__ ebuf,
                                                int* __restrict__ nbrs,
                                                int* __restrict__ kcnt,
                                                int* __restrict__ Sg) {
  const int wv = threadIdx.x >> 6;
  const int lane = threadIdx.x & 63;
  const int i = blockIdx.x * 4 + wv;
  if (i >= NNODE) return;
  const int wide = detect_wide_wave(ei);
  int c = cnt[i]; c = c > CAP ? CAP : c;
  int v = (lane < c) ? ebuf[i * CAP + lane] : 0x7FFFFFFF;
#pragma unroll
  for (int k = 2; k <= 64; k <<= 1) {
#pragma unroll
    for (int j = k >> 1; j > 0; j >>= 1) {
      int pv = __shfl_xor(v, j, 64);
      bool up = ((lane & k) == 0);
      bool lower = ((lane & j) == 0);
      int mn = v < pv ? v : pv;
      int mx = v < pv ? pv : v;
      v = (lower == up) ? mn : mx;
    }
  }
  const int m = c < KNB ? c : KNB;
  if (lane == 0) { kcnt[i] = m; Sg[i * K1] = i; }
  if (lane < KNB) {
    int d = 0;
    if (lane < m) d = wide ? ei[2 * (NEDGE + v)] : ei[NEDGE + v];
    nbrs[i * KNB + lane] = d;
    Sg[i * K1 + 1 + lane] = d;
  }
}

// ---------- C1 bitmasks: one thread per (node, row) ----------
__global__ void __launch_bounds__(256) k_c1b(const int* __restrict__ nbrs,
                                             const int* __restrict__ kcnt,
                                             const int* __restrict__ Sg,
                                             unsigned int* __restrict__ bitsG,
                                             float* __restrict__ Ag) {
  int idx = blockIdx.x * 256 + threadIdx.x;
  if (idx >= NNODE * K1) return;
  int i = idx / K1;
  int a = idx - i * K1;
  int kc = kcnt[i];
  unsigned int vmask = (kc >= KNB) ? 0x1FFFFu : ((2u << kc) - 1u);
  unsigned int bits = 0;
  bool va = (a == 0) || (a - 1 < kc);
  if (va) {
    int S[K1];
#pragma unroll
    for (int b = 0; b < K1; ++b) S[b] = Sg[i * K1 + b];
    int u = S[a];
    int ku = kcnt[u];
    const int* np = nbrs + (size_t)u * KNB;
    for (int j = 0; j < ku; ++j) {
      int w = np[j];
#pragma unroll
      for (int b = 0; b < K1; ++b) bits |= (S[b] == w) ? (1u << b) : 0u;
    }
    bits &= vmask;
  }
  bitsG[idx] = bits;
  Ag[idx] = (float)__popc(bits) / (float)(1 + kc);
}

// ---------- FGW main: flat pair list, TWO pairs per 10-lane slot (ILP x2) ----------
// R4 fix of the R3 regression: per-node tables are loaded ONCE at init and
// HELD (Kb fused-base + Tp in regs; bitmasks in a per-slot LDS region);
// k==5 reloads once (R2-proven, ~19 MB total fetch).  c2v is re-read per
// k-step from the 4 KB L2-hot tmpl via a laundered offset (keeps it out of
// the persistent register set).
// Per-slot LDS (stride 452 dwords; 452 mod 32 = 4 spreads slot banks):
//   KT rows: row a: A at [24a..24a+9], B at [24a+12..24a+21]  (a=0..16, <=405)
//   overlays (inside KT region, dead when reused — R3-identical offsets):
//     u [0..39] (f32x4 at 4b), g [44..67], w [68..87], f [88..127], acc [128..147]
//   bw ints at [408 + pp*17 + a]  (written once at init, broadcast-read)
// Whole LDS is zero-initialized at entry: the deliberate junk reads of pad
// rows 17..19 can never see NaN (R3 survived uninit LDS only by layout luck).
#define SLOT_STRIDE 452
#define SH_DWORDS   6360   /* 14*452=6328; max junk read 13*452+477=6353 */

__global__ void __launch_bounds__(128, 2) k_main(
    const float* __restrict__ tmpl,
    const int* __restrict__ kcnt, const int* __restrict__ Sg,
    const unsigned int* __restrict__ bitsG, const float* __restrict__ Ag,
    const float* __restrict__ dots, const float* __restrict__ nxv,
    const float* __restrict__ nF2, const float* __restrict__ Bq,
    float* __restrict__ out)
{
  __shared__ float SH[SH_DWORDS];

  // zero-init LDS (cross-wave region split -> needs the one barrier)
  for (int i = threadIdx.x; i < SH_DWORDS; i += 128) SH[i] = 0.f;
  __syncthreads();

  const int wv = threadIdx.x >> 6;
  const int lane = threadIdx.x & 63;
  const int p0 = lane / 10;              // 0..6 (6 = dummy slot, lanes 60-63)
  const int b = lane - p0 * 10;          // 0..9
  const int base2 = (blockIdx.x * 12 + wv * 6 + p0) * 2;
  const bool act = (p0 < 6) && (base2 < NPAIR);

  float* const KTp = &SH[(wv * 7 + p0) * SLOT_STRIDE];

  int   nodeV[2], tIv[2], kcV[2];
  float lp_r0[2], lp_r1[2];
  f32x2 Kb2v[2][8]; float kb16[2];       // fused KB_SCALE*(0.5*M + Ag + Bq)
  f32x2 Tp2[2][10];

#pragma unroll
  for (int pp = 0; pp < 2; ++pp) {
    const int pair = act ? (base2 + pp) : 0;   // clamp: no OOB global reads
    const int node = pair / 10;
    const int tI = pair - node * 10;
    const int tb = tI * TN + b;
    nodeV[pp] = node; tIv[pp] = tI;
    const int kc = kcnt[node];
    kcV[pp] = kc;
    const float cnt1 = (float)(1 + kc);
    const float inv_cnt1 = 1.f / cnt1;
    const float logp2v = -LOG2F(cnt1);
    lp_r0[pp] = ((b == 0) || (b - 1 < kc)) ? logp2v : NEG_BIG;
    lp_r1[pp] = ((9 + b) < kc) ? logp2v : NEG_BIG;
    const float Bb = Bq[tb];
    const float nf2b = nF2[tb];
#pragma unroll
    for (int j = 0; j < 10; ++j) Tp2[pp][j] = mk2(0.f, 0.f);
#pragma unroll
    for (int a = 0; a < K1; ++a) {
      bool va = (a == 0) || (a - 1 < kc);
      int sa = Sg[node * K1 + a];
      float Ma = (va ? (nxv[sa] - 2.f * dots[(size_t)sa * (NT * TN) + tb]) : 0.f) + nf2b;
      float basev = 0.5f * Ma + Ag[node * K1 + a] + Bb;
      float kv = KB_SCALE * basev;
      float tv = va ? (inv_cnt1 * 0.1f) : 0.f;
      if (a == 16) kb16[pp] = kv;
      else if (a & 1) Kb2v[pp][a >> 1].y = kv;
      else Kb2v[pp][a >> 1].x = kv;
      if (a < 10) Tp2[pp][a].x = tv; else Tp2[pp][a - 10].y = tv;
    }
    // bitmasks -> per-slot LDS (lane b covers rows b and 10+b)
    ((unsigned*)KTp)[408 + pp * 17 + b] = bitsG[node * K1 + b];
    if (b < 7)
      ((unsigned*)KTp)[408 + pp * 17 + 10 + b] = bitsG[node * K1 + 10 + b];
  }
  CBAR();

  int tmoff0 = (tIv[0] * TN + b) * TN;   // laundered per-k-step tmpl offsets
  int tmoff1 = (tIv[1] * TN + b) * TN;

#pragma unroll 1
  for (int k = 0; k < 6; ++k) {
    CBAR();
    // ---- c2v: re-read from L2-hot tmpl (laundered so it is NOT hoisted) ----
    asm volatile("" : "+v"(tmoff0), "+v"(tmoff1));
    f32x2 c2v[2][5];
    {
      const f32x2* cp0 = (const f32x2*)(tmpl + tmoff0);
      const f32x2* cp1 = (const f32x2*)(tmpl + tmoff1);
#pragma unroll
      for (int j = 0; j < 5; ++j) { c2v[0][j] = cp0[j]; c2v[1][j] = cp1[j]; }
    }
    // ---- stage Tp into KT (row-major, A|B halves) ----
#pragma unroll
    for (int pp = 0; pp < 2; ++pp) {
      float* kt = KTp + pp * 12;
#pragma unroll
      for (int a = 0; a < K1; ++a)
        kt[a * 24 + b] = (a < 10) ? Tp2[pp][a].x : Tp2[pp][a - 10].y;
    }
    CBAR();
    // ---- R = Tp @ C2^T ----
    float R[2][K1];
#pragma unroll
    for (int pp = 0; pp < 2; ++pp) {
#pragma unroll
      for (int c = 0; c < K1; ++c) {
        const float* row = &KTp[c * 24 + pp * 12];
        f32x4 u0 = *(const f32x4*)row;
        f32x4 u1 = *(const f32x4*)(row + 4);
        f32x2 u2 = *(const f32x2*)(row + 8);
        f32x2 aA = pk_mul(lo2(u0), c2v[pp][0]);
        aA = pk_fma(hi2(u0), c2v[pp][1], aA);
        f32x2 aB = pk_mul(lo2(u1), c2v[pp][2]);
        aB = pk_fma(hi2(u1), c2v[pp][3], aB);
        aA = pk_fma(u2, c2v[pp][4], aA);
        aA = pk_add(aA, aB);
        R[pp][c] = aA.x + aA.y;
      }
    }
    // ---- cross = C1 @ R (bitmasks from LDS) + held base -> logK ----
    f32x2 Kc2v[2][8]; float k16[2];
#pragma unroll
    for (int pp = 0; pp < 2; ++pp) {
#pragma unroll
      for (int a = 0; a < K1; ++a) {
        unsigned int m = ((const unsigned*)KTp)[408 + pp * 17 + a];
        float cr = 0.f;
        if (m) {
#pragma unroll
          for (int c = 0; c < K1; ++c)
            if (m & (1u << c)) cr += R[pp][c];
        }
        float basev = (a == 16) ? kb16[pp] : ((a & 1) ? Kb2v[pp][a >> 1].y : Kb2v[pp][a >> 1].x);
        float val = basev + CR_SCALE * cr;
        if (a == 16) k16[pp] = val;
        else if (a & 1) Kc2v[pp][a >> 1].y = val;
        else Kc2v[pp][a >> 1].x = val;
      }
    }

    if (k == 5) {  // final distance (one-time table reload, R2-proven cost)
#pragma unroll
      for (int pp = 0; pp < 2; ++pp) {
        const int node = nodeV[pp]; const int kc = kcV[pp];
        const int tb = tIv[pp] * TN + b;
        const int* sgp = &Sg[node * K1];
        const float nf2b = nF2[tb];
        float acc = 0.f;
#pragma unroll
        for (int a = 0; a < K1; ++a) {
          bool va = (a == 0) || (a - 1 < kc);
          int sa = sgp[a];
          float Ma = (va ? (nxv[sa] - 2.f * dots[(size_t)sa * (NT * TN) + tb]) : 0.f) + nf2b;
          float kcv = (a == 16) ? k16[pp] : ((a & 1) ? Kc2v[pp][a >> 1].y : Kc2v[pp][a >> 1].x);
          float tpv = (a < 10) ? Tp2[pp][a].x : Tp2[pp][a - 10].y;
          acc += tpv * (0.25f * Ma + 0.5f * (G_SCALE * kcv));
        }
        KTp[128 + 10 * pp + b] = acc;
      }
      CBAR();
      if (act && b < 2) {
        const float* ap = &KTp[128 + 10 * b];
        float s = 0.f;
#pragma unroll
        for (int j = 0; j < TN; ++j) s += ap[j];
        int nodeS = b ? nodeV[1] : nodeV[0];
        int tIS = b ? tIv[1] : tIv[0];
        out[nodeS * NT + tIS] = s;
      }
      return;
    }

    // ---- stage logK, read back rows b and 10+b ----
    CBAR();
#pragma unroll
    for (int pp = 0; pp < 2; ++pp) {
      float* kt = KTp + pp * 12;
#pragma unroll
      for (int a = 0; a < 16; ++a) kt[a * 24 + b] = (a & 1) ? Kc2v[pp][a >> 1].y : Kc2v[pp][a >> 1].x;
      kt[16 * 24 + b] = k16[pp];
    }
    CBAR();
    f32x2 Kr0v[2][5], Kr1v[2][5];
#pragma unroll
    for (int pp = 0; pp < 2; ++pp) {
      const float* r0 = &KTp[b * 24 + pp * 12];
      f32x4 u0 = *(const f32x4*)r0;
      f32x4 u1 = *(const f32x4*)(r0 + 4);
      f32x2 u2 = *(const f32x2*)(r0 + 8);
      Kr0v[pp][0] = lo2(u0); Kr0v[pp][1] = hi2(u0);
      Kr0v[pp][2] = lo2(u1); Kr0v[pp][3] = hi2(u1);
      Kr0v[pp][4] = u2;
      // b>=7: rows 17..19 read in-bounds junk (zero-init'd / stale, finite);
      // those rows' u is forced to 0 via P01 below.
      const float* r1 = &KTp[(10 + b) * 24 + pp * 12];
      f32x4 w0 = *(const f32x4*)r1;
      f32x4 w1 = *(const f32x4*)(r1 + 4);
      f32x2 w2 = *(const f32x2*)(r1 + 8);
      Kr1v[pp][0] = lo2(w0); Kr1v[pp][1] = hi2(w0);
      Kr1v[pp][2] = lo2(w1); Kr1v[pp][3] = hi2(w1);
      Kr1v[pp][4] = w2;
    }

    // ---- Sinkhorn iters 1-2 in log domain ----
    f32x2 gr[2][5];
    float g2v[2], fr0v[2], fr1v[2];
#pragma unroll 1
    for (int it = 0; it < 2; ++it) {
#pragma unroll
      for (int pp = 0; pp < 2; ++pp) {
        f32x2 v[8]; float v16;
        if (it == 0) {
#pragma unroll
          for (int i = 0; i < 8; ++i) v[i] = Kc2v[pp][i];
          v16 = k16[pp];
        } else {
          const float* fb = &KTp[88 + pp * 20];
          f32x4 f0 = *(const f32x4*)fb;
          f32x4 f1 = *(const f32x4*)(fb + 4);
          f32x4 f2 = *(const f32x4*)(fb + 8);
          f32x4 f3 = *(const f32x4*)(fb + 12);
          float fx = fb[16];
          v[0] = pk_add(Kc2v[pp][0], lo2(f0));
          v[1] = pk_add(Kc2v[pp][1], hi2(f0));
          v[2] = pk_add(Kc2v[pp][2], lo2(f1));
          v[3] = pk_add(Kc2v[pp][3], hi2(f1));
          v[4] = pk_add(Kc2v[pp][4], lo2(f2));
          v[5] = pk_add(Kc2v[pp][5], hi2(f2));
          v[6] = pk_add(Kc2v[pp][6], lo2(f3));
          v[7] = pk_add(Kc2v[pp][7], hi2(f3));
          v16 = k16[pp] + fx;
        }
        f32x2 m01 = pk_max(pk_max(v[0], v[1]), pk_max(v[2], v[3]));
        f32x2 m23 = pk_max(pk_max(v[4], v[5]), pk_max(v[6], v[7]));
        f32x2 mm = pk_max(m01, m23);
        float mx = fmaxf(fmaxf(mm.x, mm.y), v16);
        f32x2 mxb = mk2(mx, mx);
        f32x2 ssA = pk_exp2(pk_sub(v[0], mxb));
        ssA = pk_add(ssA, pk_exp2(pk_sub(v[1], mxb)));
        ssA = pk_add(ssA, pk_exp2(pk_sub(v[2], mxb)));
        ssA = pk_add(ssA, pk_exp2(pk_sub(v[3], mxb)));
        f32x2 ssB = pk_exp2(pk_sub(v[4], mxb));
        ssB = pk_add(ssB, pk_exp2(pk_sub(v[5], mxb)));
        ssB = pk_add(ssB, pk_exp2(pk_sub(v[6], mxb)));
        ssB = pk_add(ssB, pk_exp2(pk_sub(v[7], mxb)));
        f32x2 ss = pk_add(ssA, ssB);
        float s = ss.x + ss.y + EXP2F(v16 - mx);
        g2v[pp] = LOGQ2 - mx - LOG2F(s);
        KTp[44 + pp * 12 + b] = g2v[pp];
      }
      CBAR();
#pragma unroll
      for (int pp = 0; pp < 2; ++pp) {
        const float* gb = &KTp[44 + pp * 12];
        f32x4 g0 = *(const f32x4*)gb;
        f32x4 g1 = *(const f32x4*)(gb + 4);
        f32x2 gx = *(const f32x2*)(gb + 8);
        gr[pp][0] = lo2(g0); gr[pp][1] = hi2(g0);
        gr[pp][2] = lo2(g1); gr[pp][3] = hi2(g1);
        gr[pp][4] = gx;
        f32x2 w0[5], w1[5];
#pragma unroll
        for (int j = 0; j < 5; ++j) w0[j] = pk_add(Kr0v[pp][j], gr[pp][j]);
#pragma unroll
        for (int j = 0; j < 5; ++j) w1[j] = pk_add(Kr1v[pp][j], gr[pp][j]);
        f32x2 a01 = pk_max(pk_max(w0[0], w0[1]), pk_max(w0[2], w0[3]));
        a01 = pk_max(a01, w0[4]);
        float mxa = fmaxf(a01.x, a01.y);
        f32x2 b01 = pk_max(pk_max(w1[0], w1[1]), pk_max(w1[2], w1[3]));
        b01 = pk_max(b01, w1[4]);
        float mxb2 = fmaxf(b01.x, b01.y);
        f32x2 mab = mk2(mxa, mxa);
        f32x2 mbb = mk2(mxb2, mxb2);
        f32x2 sx = pk_exp2(pk_sub(w0[0], mab));
        sx = pk_add(sx, pk_exp2(pk_sub(w0[1], mab)));
        sx = pk_add(sx, pk_exp2(pk_sub(w0[2], mab)));
        sx = pk_add(sx, pk_exp2(pk_sub(w0[3], mab)));
        sx = pk_add(sx, pk_exp2(pk_sub(w0[4], mab)));
        f32x2 sy = pk_exp2(pk_sub(w1[0], mbb));
        sy = pk_add(sy, pk_exp2(pk_sub(w1[1], mbb)));
        sy = pk_add(sy, pk_exp2(pk_sub(w1[2], mbb)));
        sy = pk_add(sy, pk_exp2(pk_sub(w1[3], mbb)));
        sy = pk_add(sy, pk_exp2(pk_sub(w1[4], mbb)));
        fr0v[pp] = lp_r0[pp] - mxa - LOG2F(sx.x + sx.y);
        fr1v[pp] = lp_r1[pp] - mxb2 - LOG2F(sy.x + sy.y);
        KTp[88 + pp * 20 + b] = fr0v[pp];
        KTp[88 + pp * 20 + 10 + b] = fr1v[pp];   // b>=7 -> pad slots, never consumed
      }
      CBAR();
    }

    // ---- stabilized kernels from (f2, g2) snapshot ----
    f32x2 Kcs2[2][10];
    f32x2 Krs01[2][10];
    float P00[2], P01[2], Q0[2];
#pragma unroll
    for (int pp = 0; pp < 2; ++pp) {
      const float* fb = &KTp[88 + pp * 20];
      f32x4 F0 = *(const f32x4*)fb;
      f32x4 F1 = *(const f32x4*)(fb + 4);
      f32x4 F2 = *(const f32x4*)(fb + 8);
      f32x4 F3 = *(const f32x4*)(fb + 12);
      float f16v = fb[16];
      float fs[K1];
      fs[0] = F0.x; fs[1] = F0.y; fs[2] = F0.z; fs[3] = F0.w;
      fs[4] = F1.x; fs[5] = F1.y; fs[6] = F1.z; fs[7] = F1.w;
      fs[8] = F2.x; fs[9] = F2.y; fs[10] = F2.z; fs[11] = F2.w;
      fs[12] = F3.x; fs[13] = F3.y; fs[14] = F3.z; fs[15] = F3.w;
      fs[16] = f16v;
      float qs[K1];
#pragma unroll
      for (int a = 0; a < K1; ++a) {
        float kcv = (a == 16) ? k16[pp] : ((a & 1) ? Kc2v[pp][a >> 1].y : Kc2v[pp][a >> 1].x);
        qs[a] = kcv + fs[a];
      }
      float sigma = qs[0];
#pragma unroll
      for (int a = 1; a < K1; ++a) sigma = fmaxf(sigma, qs[a]);
#pragma unroll
      for (int j = 0; j < 10; ++j) {
        float kx = EXP2F(qs[j] - sigma);
        float ky = (j < 7) ? EXP2F(qs[10 + j] - sigma) : 0.f;
        Kcs2[pp][j] = mk2(kx, ky);
      }
      Q0[pp] = EXP2F(clamp120(LOGQ2 - sigma - g2v[pp]));
      f32x2 a0[5], a1[5];
#pragma unroll
      for (int j = 0; j < 5; ++j) a0[j] = pk_add(Kr0v[pp][j], gr[pp][j]);
#pragma unroll
      for (int j = 0; j < 5; ++j) a1[j] = pk_add(Kr1v[pp][j], gr[pp][j]);
      f32x2 r0m = pk_max(pk_max(a0[0], a0[1]), pk_max(a0[2], a0[3]));
      r0m = pk_max(r0m, a0[4]);
      float rho0 = fmaxf(r0m.x, r0m.y);
      f32x2 r1m = pk_max(pk_max(a1[0], a1[1]), pk_max(a1[2], a1[3]));
      r1m = pk_max(r1m, a1[4]);
      float rho1 = fmaxf(r1m.x, r1m.y);
#pragma unroll
      for (int j = 0; j < 5; ++j) {
        Krs01[pp][2 * j]     = mk2(EXP2F(a0[j].x - rho0), EXP2F(a1[j].x - rho1));
        Krs01[pp][2 * j + 1] = mk2(EXP2F(a0[j].y - rho0), EXP2F(a1[j].y - rho1));
      }
      P00[pp] = EXP2F(clamp120((lp_r0[pp] - rho0) - fr0v[pp]));
      // pad rows (17..19): force u==0 so junk can never poison real columns.
      P01[pp] = (b < 7) ? EXP2F(clamp120((lp_r1[pp] - rho1) - fr1v[pp])) : 0.f;
    }

    // ---- Sinkhorn iters 3..20: multiplicative, combined u/w exchange ----
    float Slast[2], t0v[2], t1v[2];
    {  // peeled iter 3: u == 1
      float wb2[2];
#pragma unroll
      for (int pp = 0; pp < 2; ++pp) {
        f32x2 SA = pk_add(pk_add(Kcs2[pp][0], Kcs2[pp][1]), pk_add(Kcs2[pp][2], Kcs2[pp][3]));
        f32x2 SB = pk_add(pk_add(Kcs2[pp][4], Kcs2[pp][5]), pk_add(Kcs2[pp][6], Kcs2[pp][7]));
        f32x2 S2 = pk_add(pk_add(SA, SB), pk_add(Kcs2[pp][8], Kcs2[pp][9]));
        float S = fmaxf(S2.x + S2.y, TINYF);
        Slast[pp] = S;
        wb2[pp] = Q0[pp] * RCPF(S);
      }
      *(f32x2*)&KTp[68 + 2 * b] = mk2(wb2[0], wb2[1]);
      CBAR();
      f32x4 Wq[5];
#pragma unroll
      for (int i = 0; i < 5; ++i) Wq[i] = *(const f32x4*)&KTp[68 + 4 * i];
#pragma unroll
      for (int pp = 0; pp < 2; ++pp) {
        float w0 = pp ? Wq[0].y : Wq[0].x, w1 = pp ? Wq[0].w : Wq[0].z;
        float w2 = pp ? Wq[1].y : Wq[1].x, w3 = pp ? Wq[1].w : Wq[1].z;
        float w4 = pp ? Wq[2].y : Wq[2].x, w5 = pp ? Wq[2].w : Wq[2].z;
        float w6 = pp ? Wq[3].y : Wq[3].x, w7 = pp ? Wq[3].w : Wq[3].z;
        float w8 = pp ? Wq[4].y : Wq[4].x, w9 = pp ? Wq[4].w : Wq[4].z;
        f32x2 tA = pk_mul(Krs01[pp][0], mk2(w0, w0));
        tA = pk_fma(Krs01[pp][1], mk2(w1, w1), tA);
        tA = pk_fma(Krs01[pp][2], mk2(w2, w2), tA);
        tA = pk_fma(Krs01[pp][3], mk2(w3, w3), tA);
        tA = pk_fma(Krs01[pp][4], mk2(w4, w4), tA);
        f32x2 tB = pk_mul(Krs01[pp][5], mk2(w5, w5));
        tB = pk_fma(Krs01[pp][6], mk2(w6, w6), tB);
        tB = pk_fma(Krs01[pp][7], mk2(w7, w7), tB);
        tB = pk_fma(Krs01[pp][8], mk2(w8, w8), tB);
        tB = pk_fma(Krs01[pp][9], mk2(w9, w9), tB);
        f32x2 t01 = pk_add(tA, tB);
        t0v[pp] = t01.x; t1v[pp] = t01.y;
      }
    }
#pragma unroll 1
    for (int it = 0; it < 17; ++it) {   // iters 4..20
      float u0A = P00[0] * RCPF(fmaxf(t0v[0], TINYF));
      float u1A = P01[0] * RCPF(fmaxf(t1v[0], TINYF));
      float u0B = P00[1] * RCPF(fmaxf(t0v[1], TINYF));
      float u1B = P01[1] * RCPF(fmaxf(t1v[1], TINYF));
      f32x4 uw; uw.x = u0A; uw.y = u1A; uw.z = u0B; uw.w = u1B;
      *(f32x4*)&KTp[4 * b] = uw;       // ONE b128 write for both pairs
      CBAR();
      f32x2 SA0 = mk2(0.f, 0.f), SB0 = mk2(0.f, 0.f);
      f32x2 SA1 = mk2(0.f, 0.f), SB1 = mk2(0.f, 0.f);
#pragma unroll
      for (int j = 0; j < 10; ++j) {
        f32x4 U = *(const f32x4*)&KTp[4 * j];
        if (j < 5) { SA0 = pk_fma(Kcs2[0][j], lo2(U), SA0); SA1 = pk_fma(Kcs2[1][j], hi2(U), SA1); }
        else       { SB0 = pk_fma(Kcs2[0][j], lo2(U), SB0); SB1 = pk_fma(Kcs2[1][j], hi2(U), SB1); }
      }
      float wb2[2];
      {
        f32x2 S20 = pk_add(SA0, SB0);
        float S0 = fmaxf(S20.x + S20.y, TINYF);
        Slast[0] = S0; wb2[0] = Q0[0] * RCPF(S0);
        f32x2 S21 = pk_add(SA1, SB1);
        float S1 = fmaxf(S21.x + S21.y, TINYF);
        Slast[1] = S1; wb2[1] = Q0[1] * RCPF(S1);
      }
      *(f32x2*)&KTp[68 + 2 * b] = mk2(wb2[0], wb2[1]);
      CBAR();
      f32x4 Wq[5];
#pragma unroll
      for (int i = 0; i < 5; ++i) Wq[i] = *(const f32x4*)&KTp[68 + 4 * i];
#pragma unroll
      for (int pp = 0; pp < 2; ++pp) {
        float w0 = pp ? Wq[0].y : Wq[0].x, w1 = pp ? Wq[0].w : Wq[0].z;
        float w2 = pp ? Wq[1].y : Wq[1].x, w3 = pp ? Wq[1].w : Wq[1].z;
        float w4 = pp ? Wq[2].y : Wq[2].x, w5 = pp ? Wq[2].w : Wq[2].z;
        float w6 = pp ? Wq[3].y : Wq[3].x, w7 = pp ? Wq[3].w : Wq[3].z;
        float w8 = pp ? Wq[4].y : Wq[4].x, w9 = pp ? Wq[4].w : Wq[4].z;
        f32x2 tA = pk_mul(Krs01[pp][0], mk2(w0, w0));
        tA = pk_fma(Krs01[pp][1], mk2(w1, w1), tA);
        tA = pk_fma(Krs01[pp][2], mk2(w2, w2), tA);
        tA = pk_fma(Krs01[pp][3], mk2(w3, w3), tA);
        tA = pk_fma(Krs01[pp][4], mk2(w4, w4), tA);
        f32x2 tB = pk_mul(Krs01[pp][5], mk2(w5, w5));
        tB = pk_fma(Krs01[pp][6], mk2(w6, w6), tB);
        tB = pk_fma(Krs01[pp][7], mk2(w7, w7), tB);
        tB = pk_fma(Krs01[pp][8], mk2(w8, w8), tB);
        tB = pk_fma(Krs01[pp][9], mk2(w9, w9), tB);
        f32x2 t01 = pk_add(tA, tB);
        t0v[pp] = t01.x; t1v[pp] = t01.y;
      }
    }

    // ---- final u + FW transport update: Tn = u * Kcs * (0.1/Slast) ----
    {
      float u0A = P00[0] * RCPF(fmaxf(t0v[0], TINYF));
      float u1A = P01[0] * RCPF(fmaxf(t1v[0], TINYF));
      float u0B = P00[1] * RCPF(fmaxf(t0v[1], TINYF));
      float u1B = P01[1] * RCPF(fmaxf(t1v[1], TINYF));
      f32x4 uw; uw.x = u0A; uw.y = u1A; uw.z = u0B; uw.w = u1B;
      *(f32x4*)&KTp[4 * b] = uw;
      CBAR();
      const float gam = 2.f / ((float)k + 2.f);
      const float om = 1.f - gam;
      const f32x2 omb = mk2(om, om);
      const float gs0 = gam * 0.1f * RCPF(Slast[0]);
      const float gs1 = gam * 0.1f * RCPF(Slast[1]);
      const f32x2 gsb0 = mk2(gs0, gs0);
      const f32x2 gsb1 = mk2(gs1, gs1);
#pragma unroll
      for (int j = 0; j < 10; ++j) {
        f32x4 U = *(const f32x4*)&KTp[4 * j];
        Tp2[0][j] = pk_fma(omb, Tp2[0][j], pk_mul(gsb0, pk_mul(Kcs2[0][j], lo2(U))));
        Tp2[1][j] = pk_fma(omb, Tp2[1][j], pk_mul(gsb1, pk_mul(Kcs2[1][j], hi2(U))));
      }
    }
  }
}

extern "C" void kernel_launch(void* const* d_in, const int* in_sizes, int n_in,
                              void* d_out, int out_size, void* d_ws, size_t ws_size,
                              hipStream_t stream) {
  const float* x    = (const float*)d_in[0];
  const int*   ei   = (const int*)d_in[1];
  const float* tmpl = (const float*)d_in[2];
  const float* tf   = (const float*)d_in[3];
  float* out = (float*)d_out;

  int* cnt  = (int*)d_ws;
  int* ebuf = cnt + NNODE;
  int* nbrs = ebuf + (size_t)NNODE * CAP;
  int* kcnt = nbrs + (size_t)NNODE * KNB;
  int* Sg   = kcnt + NNODE;
  unsigned int* bits = (unsigned int*)(Sg + (size_t)NNODE * K1);
  float* Ag   = (float*)(bits + (size_t)NNODE * K1);
  float* dots = Ag + (size_t)NNODE * K1;
  float* nxv  = dots + (size_t)NNODE * (NT * TN);
  float* nF2  = nxv + NNODE;
  float* Bq   = nF2 + NT * TN;

  hipMemsetAsync(cnt, 0, NNODE * sizeof(int), stream);
  k_prep<<<625 + (NNODE + 15) / 16, 256, 0, stream>>>(ei, cnt, ebuf, x, tf, tmpl,
                                                      dots, nxv, nF2, Bq);
  k_select<<<(NNODE + 3) / 4, 256, 0, stream>>>(ei, cnt, ebuf, nbrs, kcnt, Sg);
  k_c1b<<<(NNODE * K1 + 255) / 256, 256, 0, stream>>>(nbrs, kcnt, Sg, bits, Ag);
  k_main<<<(NPAIR + 23) / 24, 128, 0, stream>>>(tmpl, kcnt, Sg, bits, Ag, dots, nxv, nF2, Bq, out);
}

// Round 6
// 510.701 us; speedup vs baseline: 2.7389x; 1.6280x over previous
//
#include <hip/hip_runtime.h>
#include <math.h>

#define NNODE 10000
#define NEDGE 160000
#define KNB   16
#define K1    17
#define NT    10
#define TN    10
#define DF    128
#define CAP   64
#define NPAIR (NNODE * NT)   /* 100000 (node,template) pairs */
#define NEG_BIG (-1e9f)

#define LOGQ2      (-3.32192809489f)   /* log2(0.1) */
#define KB_SCALE   (-14.4269504089f)   /* -10*log2e  */
#define CR_SCALE   (28.8539008178f)    /* +20*log2e  */
#define G_SCALE    (-0.069314718056f)  /* -ln2/10    */
#define LN2        0.69314718056f
#define TINYF      1e-30f

#if defined(__has_builtin)
#if __has_builtin(__builtin_amdgcn_exp2f)
#define EXP2F(x) __builtin_amdgcn_exp2f(x)
#endif
#if __has_builtin(__builtin_amdgcn_rcpf)
#define RCPF(x) __builtin_amdgcn_rcpf(x)
#endif
#endif
#ifndef EXP2F
#define EXP2F(x) __expf((x) * LN2)
#endif
#ifndef RCPF
#define RCPF(x) (1.0f / (x))
#endif
#define LOG2F(x) __log2f(x)

// Compiler-only barrier: DS ops from one wave execute IN ORDER in the LDS
// pipeline; compiler still emits lgkmcnt(N) before VALU consumes read data.
// All LDS traffic here is slot-private and slots never span waves.
#define CBAR() asm volatile("" ::: "memory")

// Packed fp32: gfx90a+/gfx950 have full-rate v_pk_{fma,mul,add}_f32.
// LLVM selects them for <2 x float> ops ONLY from ext_vector types; HIP's
// struct float2 compiles to 2 scalar VALU ops.  This kernel is VALU-bound,
// so all pair math uses f32x2.
typedef float f32x2 __attribute__((ext_vector_type(2)));

__device__ __forceinline__ f32x2 mk2(float x, float y) { f32x2 r; r.x = x; r.y = y; return r; }
__device__ __forceinline__ f32x2 pk_add(f32x2 a, f32x2 b) { return a + b; }            // v_pk_add_f32
__device__ __forceinline__ f32x2 pk_sub(f32x2 a, f32x2 b) { return a - b; }            // v_pk_add_f32 (neg)
__device__ __forceinline__ f32x2 pk_mul(f32x2 a, f32x2 b) { return a * b; }            // v_pk_mul_f32
__device__ __forceinline__ f32x2 pk_fma(f32x2 a, f32x2 b, f32x2 c) {                   // v_pk_fma_f32
  return __builtin_elementwise_fma(a, b, c);
}
__device__ __forceinline__ f32x2 pk_max(f32x2 a, f32x2 b) {                            // no packed f32 max
  return mk2(fmaxf(a.x, b.x), fmaxf(a.y, b.y));
}
__device__ __forceinline__ f32x2 pk_exp2(f32x2 a) { return mk2(EXP2F(a.x), EXP2F(a.y)); }
__device__ __forceinline__ float clamp120(float x) { return fminf(120.f, fmaxf(-120.f, x)); }

// int64-vs-int32 sniff, computed by ONE lane and broadcast
__device__ __forceinline__ int detect_wide_wave(const int* ei) {
  int z = 0;
  if ((threadIdx.x & 63) == 0) {
#pragma unroll
    for (int i = 0; i < 32; ++i) z |= ei[2 * i + 1];
  }
  z = __shfl(z, 0, 64);
  return z == 0;
}

// ---------- fused: edge bucketing + feature dots (16-node tiles) + template stats ----------
__global__ void __launch_bounds__(256) k_prep(const int* __restrict__ ei,
                                              int* cnt, int* ebuf,
                                              const float* __restrict__ x,
                                              const float* __restrict__ tf,
                                              const float* __restrict__ tmpl,
                                              float* __restrict__ dots,
                                              float* __restrict__ nxv,
                                              float* __restrict__ nF2,
                                              float* __restrict__ Bq) {
  __shared__ float xs[16][DF];   // 8 KB
  const int tid = threadIdx.x;
  if (blockIdx.x < 625) {          // hist: 625*256 == NEDGE
    int wide = detect_wide_wave(ei);
    int e = blockIdx.x * 256 + tid;
    int s = wide ? ei[2 * e] : ei[e];
    int pos = atomicAdd(&cnt[s], 1);
    if (pos < CAP) ebuf[s * CAP + pos] = e;   // node-major: wave-coalesced select reads
    return;
  }
  const int db = blockIdx.x - 625;
  if (db == 0 && tid < NT * TN) {  // template stats, once
    const float* fp = tf + (size_t)tid * DF;
    float s = 0.f;
    for (int d = 0; d < DF; ++d) { float v = fp[d]; s += v * v; }
    nF2[tid] = s;
    const float* cp = tmpl + (size_t)tid * TN;
    float s2 = 0.f;
    for (int c = 0; c < TN; ++c) { float v = cp[c]; s2 += v * v; }
    Bq[tid] = 0.1f * s2;
  }
  const int nb = db * 16;
  const int nvalid = (NNODE - nb) < 16 ? (NNODE - nb) : 16;
  {
    const float4* xg = (const float4*)(x + (size_t)nb * DF);
    float4* xl = (float4*)&xs[0][0];
    for (int i = tid; i < nvalid * (DF / 4); i += 256) xl[i] = xg[i];
  }
  __syncthreads();
  for (int o = tid; o < nvalid * (NT * TN); o += 256) {
    int n = o / (NT * TN);
    int tb = o - n * (NT * TN);
    const float4* fp = (const float4*)(tf + (size_t)tb * DF);
    const float4* xp = (const float4*)&xs[n][0];
    float s = 0.f;
#pragma unroll
    for (int d = 0; d < DF / 4; ++d) {
      float4 a = xp[d], f = fp[d];
      s += a.x * f.x + a.y * f.y + a.z * f.z + a.w * f.w;
    }
    dots[(size_t)(nb + n) * (NT * TN) + tb] = s;
  }
  if (tid < nvalid) {
    const float4* xp = (const float4*)&xs[tid][0];
    float s = 0.f;
#pragma unroll
    for (int d = 0; d < DF / 4; ++d) {
      float4 a = xp[d];
      s += a.x * a.x + a.y * a.y + a.z * a.z + a.w * a.w;
    }
    nxv[nb + tid] = s;
  }
}

// ---------- wave-per-node: bitonic-sort 64 bucket entries, keep 16 smallest ----------
__global__ void __launch_bounds__(256) k_select(const int* __restrict__ ei,
                                                const int* __restrict__ cnt,
                                                const int* __restrict__ ebuf,
                                                int* __restrict__ nbrs,
                                                int* __restrict__ kcnt,
                                                int* __restrict__ Sg) {
  const int wv = threadIdx.x >> 6;
  const int lane = threadIdx.x & 63;
  const int i = blockIdx.x * 4 + wv;
  if (i >= NNODE) return;
  const int wide = detect_wide_wave(ei);
  int c = cnt[i]; c = c > CAP ? CAP : c;
  int v = (lane < c) ? ebuf[i * CAP + lane] : 0x7FFFFFFF;
#pragma unroll
  for (int k = 2; k <= 64; k <<= 1) {
#pragma unroll
    for (int j = k >> 1; j > 0; j >>= 1) {
      int pv = __shfl_xor(v, j, 64);
      bool up = ((lane & k) == 0);
      bool lower = ((lane & j) == 0);
      int mn = v < pv ? v : pv;
      int mx = v < pv ? pv : v;
      v = (lower == up) ? mn : mx;
    }
  }
  const int m = c < KNB ? c : KNB;
  if (lane == 0) { kcnt[i] = m; Sg[i * K1] = i; }
  if (lane < KNB) {
    int d = 0;
    if (lane < m) d = wide ? ei[2 * (NEDGE + v)] : ei[NEDGE + v];
    nbrs[i * KNB + lane] = d;
    Sg[i * K1 + 1 + lane] = d;
  }
}

// ---------- C1 bitmasks: one thread per (node, row) ----------
__global__ void __launch_bounds__(256) k_c1b(const int* __restrict__ nbrs,
                                             const int* __restrict__ kcnt,
                                             const int* __restrict__ Sg,
                                             unsigned int* __restrict__ bitsG,
                                             float* __restrict__ Ag) {
  int idx = blockIdx.x * 256 + threadIdx.x;
  if (idx >= NNODE * K1) return;
  int i = idx / K1;
  int a = idx - i * K1;
  int kc = kcnt[i];
  unsigned int vmask = (kc >= KNB) ? 0x1FFFFu : ((2u << kc) - 1u);
  unsigned int bits = 0;
  bool va = (a == 0) || (a - 1 < kc);
  if (va) {
    int S[K1];
#pragma unroll
    for (int b = 0; b < K1; ++b) S[b] = Sg[i * K1 + b];
    int u = S[a];
    int ku = kcnt[u];
    const int* np = nbrs + (size_t)u * KNB;
    for (int j = 0; j < ku; ++j) {
      int w = np[j];
#pragma unroll
      for (int b = 0; b < K1; ++b) bits |= (S[b] == w) ? (1u << b) : 0u;
    }
    bits &= vmask;
  }
  bitsG[idx] = bits;
  Ag[idx] = (float)__popc(bits) / (float)(1 + kc);
}

// ---------- FGW main: flat (node,template)-pair list ----------
// Block = 128 threads = 2 waves; each wave = 6 REAL 10-lane slots (lanes 0-59)
// + 1 dummy slot (lanes 60-63).  60/64 lanes useful.
// Slots are fully LDS-private; fL/gL/uL/wL/accL OVERLAY the slot's KT region
// (KT is dead during the log/stab/mult phases):
//   KTp[0..203]  : KT (Tp staging, R; then logK staging, row readback)
//   KTp[0..19]   : fL (log/stab)  == uL (mult phase)
//   KTp[20..31]  : gL (log/stab)  == wL (mult phase)
//   KTp[32..41]  : accL (k==5 only)
// Proven R2 structure (388 us k_main).  R6 delta: s_setprio(1) around the
// multiplicative Sinkhorn loop — waves are barrier-free and phase-staggered
// (T5 regime: role diversity), so the CU scheduler can favor the
// LDS-round-trip-critical mult-loop waves over exp2-heavy stab-phase waves.
__global__ void __launch_bounds__(128, 3) k_main(
    const float* __restrict__ tmpl,
    const int* __restrict__ kcnt, const int* __restrict__ Sg,
    const unsigned int* __restrict__ bitsG, const float* __restrict__ Ag,
    const float* __restrict__ dots, const float* __restrict__ nxv,
    const float* __restrict__ nF2, const float* __restrict__ Bq,
    float* __restrict__ out)
{
  __shared__ float SH[2 * 7 * 204 + 16];   // stride 204 ≡ 12 mod 32 per slot

  const int wv = threadIdx.x >> 6;
  const int lane = threadIdx.x & 63;
  const int p0 = lane / 10;              // 0..6 (6 = dummy slot, lanes 60-63)
  const int b = lane - p0 * 10;          // 0..9 (0..3 in dummy slot)
  const int pairRaw = blockIdx.x * 12 + wv * 6 + p0;
  const bool act = (p0 < 6) && (pairRaw < NPAIR);
  const int pair = act ? pairRaw : 0;    // clamp: no OOB global reads
  const int node = pair / 10;
  const int tI = pair - node * 10;       // template index
  const int tb = tI * TN + b;            // row into tmpl/tf-derived tables

  float* const KTp  = &SH[(wv * 7 + p0) * 204];
  float* const fLp  = KTp;        // 20 floats
  float* const gLp  = KTp + 20;   // 12 floats
  float* const uLp  = KTp;        // 20 floats (b64 pairs (u_j, u_{10+j}))
  float* const wLp  = KTp + 20;   // 12 floats (compact w, 10 used)
  float* const accp = KTp + 32;   // 10 floats

  const int kc = kcnt[node];
  const float cnt1 = (float)(1 + kc);
  const float inv_cnt1 = 1.f / cnt1;
  const float logp2v = -LOG2F(cnt1);
  const float lp2_r0 = ((b == 0) || (b - 1 < kc)) ? logp2v : NEG_BIG;  // row b
  const float lp2_r1 = ((9 + b) < kc) ? logp2v : NEG_BIG;              // row 10+b (b>=7: pad)

  f32x2 c2v[5];
  {
    const f32x2* cp = (const f32x2*)(tmpl + (size_t)tb * TN);
#pragma unroll
    for (int j = 0; j < 5; ++j) c2v[j] = cp[j];
  }
  const float Bb = Bq[tb];
  const float nf2b = nF2[tb];

  f32x2 Kb2v[8]; float kb16;            // (2i,2i+1) pairing for log phase
  f32x2 Tp2[10];                        // (j, 10+j) pairing; .y=0 for j>=7 (pad rows)
#pragma unroll
  for (int j = 0; j < 10; ++j) Tp2[j] = mk2(0.f, 0.f);
  unsigned int bw[K1];
#pragma unroll
  for (int a = 0; a < K1; ++a) {
    bool va = (a == 0) || (a - 1 < kc);
    int sa = Sg[node * K1 + a];
    float Ma = (va ? (nxv[sa] - 2.f * dots[(size_t)sa * (NT * TN) + tb]) : 0.f) + nf2b;
    float base = 0.5f * Ma + Ag[node * K1 + a] + Bb;
    float kv = KB_SCALE * base;
    float tv = va ? (inv_cnt1 * 0.1f) : 0.f;
    if (a == 16) kb16 = kv;
    else if (a & 1) Kb2v[a >> 1].y = kv;
    else Kb2v[a >> 1].x = kv;
    if (a < 10) Tp2[a].x = tv; else Tp2[a - 10].y = tv;
    bw[a] = bitsG[node * K1 + a];
  }

  f32x2 Kc2v[8]; float k16 = 0.f;
  f32x2 Kr0v[5], Kr1v[5];
  f32x2 gr[5];
  float g2 = 0.f, fr0 = 0.f, fr1 = 0.f;

#pragma unroll 1
  for (int k = 0; k < 6; ++k) {
    // ---- stage Tp columns into KT (row-major, [a][b]) ----
#pragma unroll
    for (int a = 0; a < K1; ++a)
      KTp[a * 12 + b] = (a < 10) ? Tp2[a].x : Tp2[a - 10].y;
    CBAR();
    // ---- R = Tp @ C2^T (split chains) ----
    float R[K1];
#pragma unroll
    for (int c = 0; c < K1; ++c) {
      const float* row = &KTp[c * 12];
      float4 u0 = *(const float4*)row;
      float4 u1 = *(const float4*)(row + 4);
      f32x2 u2 = *(const f32x2*)(row + 8);
      f32x2 accA = pk_mul(mk2(u0.x, u0.y), c2v[0]);
      accA = pk_fma(mk2(u0.z, u0.w), c2v[1], accA);
      f32x2 accB = pk_mul(mk2(u1.x, u1.y), c2v[2]);
      accB = pk_fma(mk2(u1.z, u1.w), c2v[3], accB);
      accA = pk_fma(u2, c2v[4], accA);
      accA = pk_add(accA, accB);
      R[c] = accA.x + accA.y;
    }
    // ---- cross = C1 @ R via bitmasks → logK column ----
#pragma unroll
    for (int a = 0; a < K1; ++a) {
      float cr = 0.f;
      unsigned int m = bw[a];
      if (m) {
#pragma unroll
        for (int c = 0; c < K1; ++c)
          if (m & (1u << c)) cr += R[c];
      }
      float base = (a == 16) ? kb16 : ((a & 1) ? Kb2v[a >> 1].y : Kb2v[a >> 1].x);
      float val = base + CR_SCALE * cr;
      if (a == 16) k16 = val;
      else if (a & 1) Kc2v[a >> 1].y = val;
      else Kc2v[a >> 1].x = val;
    }

    if (k == 5) {  // final distance
      float acc = 0.f;
#pragma unroll
      for (int a = 0; a < K1; ++a) {
        bool va = (a == 0) || (a - 1 < kc);
        int sa = Sg[node * K1 + a];
        float Ma = (va ? (nxv[sa] - 2.f * dots[(size_t)sa * (NT * TN) + tb]) : 0.f) + nf2b;
        float kcv = (a == 16) ? k16 : ((a & 1) ? Kc2v[a >> 1].y : Kc2v[a >> 1].x);
        float tpv = (a < 10) ? Tp2[a].x : Tp2[a - 10].y;
        acc += tpv * (0.25f * Ma + 0.5f * (G_SCALE * kcv));
      }
      accp[b] = acc;
      CBAR();
      if (act && b == 0) {
        float s = 0.f;
#pragma unroll
        for (int j = 0; j < TN; ++j) s += accp[j];
        out[node * NT + tI] = s;
      }
      return;
    }

    // ---- stage logK, read back rows b and 10+b ----
    CBAR();
#pragma unroll
    for (int a = 0; a < 16; ++a) KTp[a * 12 + b] = (a & 1) ? Kc2v[a >> 1].y : Kc2v[a >> 1].x;
    KTp[16 * 12 + b] = k16;
    CBAR();
    {
      const float* r0 = &KTp[b * 12];
      float4 u0 = *(const float4*)r0;
      float4 u1 = *(const float4*)(r0 + 4);
      f32x2 u2 = *(const f32x2*)(r0 + 8);
      Kr0v[0] = mk2(u0.x, u0.y); Kr0v[1] = mk2(u0.z, u0.w);
      Kr0v[2] = mk2(u1.x, u1.y); Kr0v[3] = mk2(u1.z, u1.w);
      Kr0v[4] = u2;
      // b>=7: reads spill into the NEXT slot's region (in-bounds junk, possibly
      // NaN from the partially-written dummy slot).  Row 10+b is pure padding;
      // its u is forced to 0 via P01 below, so junk cannot reach real columns.
      const float* r1 = &KTp[(10 + b) * 12];
      float4 w0 = *(const float4*)r1;
      float4 w1 = *(const float4*)(r1 + 4);
      f32x2 w2 = *(const f32x2*)(r1 + 8);
      Kr1v[0] = mk2(w0.x, w0.y); Kr1v[1] = mk2(w0.z, w0.w);
      Kr1v[2] = mk2(w1.x, w1.y); Kr1v[3] = mk2(w1.z, w1.w);
      Kr1v[4] = w2;
    }

    // ---- Sinkhorn iters 1-2 in log domain ----
#pragma unroll 1
    for (int it = 0; it < 2; ++it) {
      f32x2 v[8]; float v16;
      if (it == 0) {
#pragma unroll
        for (int i = 0; i < 8; ++i) v[i] = Kc2v[i];
        v16 = k16;
      } else {
        float4 f0 = *(const float4*)&fLp[0];
        float4 f1 = *(const float4*)&fLp[4];
        float4 f2 = *(const float4*)&fLp[8];
        float4 f3 = *(const float4*)&fLp[12];
        float fx = fLp[16];
        v[0] = pk_add(Kc2v[0], mk2(f0.x, f0.y));
        v[1] = pk_add(Kc2v[1], mk2(f0.z, f0.w));
        v[2] = pk_add(Kc2v[2], mk2(f1.x, f1.y));
        v[3] = pk_add(Kc2v[3], mk2(f1.z, f1.w));
        v[4] = pk_add(Kc2v[4], mk2(f2.x, f2.y));
        v[5] = pk_add(Kc2v[5], mk2(f2.z, f2.w));
        v[6] = pk_add(Kc2v[6], mk2(f3.x, f3.y));
        v[7] = pk_add(Kc2v[7], mk2(f3.z, f3.w));
        v16 = k16 + fx;
      }
      f32x2 m01 = pk_max(pk_max(v[0], v[1]), pk_max(v[2], v[3]));
      f32x2 m23 = pk_max(pk_max(v[4], v[5]), pk_max(v[6], v[7]));
      f32x2 mm = pk_max(m01, m23);
      float mx = fmaxf(fmaxf(mm.x, mm.y), v16);
      f32x2 mxb = mk2(mx, mx);
      f32x2 ssA = pk_exp2(pk_sub(v[0], mxb));
      ssA = pk_add(ssA, pk_exp2(pk_sub(v[1], mxb)));
      ssA = pk_add(ssA, pk_exp2(pk_sub(v[2], mxb)));
      ssA = pk_add(ssA, pk_exp2(pk_sub(v[3], mxb)));
      f32x2 ssB = pk_exp2(pk_sub(v[4], mxb));
      ssB = pk_add(ssB, pk_exp2(pk_sub(v[5], mxb)));
      ssB = pk_add(ssB, pk_exp2(pk_sub(v[6], mxb)));
      ssB = pk_add(ssB, pk_exp2(pk_sub(v[7], mxb)));
      f32x2 ss = pk_add(ssA, ssB);
      float s = ss.x + ss.y + EXP2F(v16 - mx);
      g2 = LOGQ2 - mx - LOG2F(s);
      gLp[b] = g2;
      CBAR();
      {
        float4 g0 = *(const float4*)&gLp[0];
        float4 g1 = *(const float4*)&gLp[4];
        f32x2 gx = *(const f32x2*)&gLp[8];
        gr[0] = mk2(g0.x, g0.y); gr[1] = mk2(g0.z, g0.w);
        gr[2] = mk2(g1.x, g1.y); gr[3] = mk2(g1.z, g1.w);
        gr[4] = gx;
      }
      f32x2 w0[5], w1[5];
#pragma unroll
      for (int j = 0; j < 5; ++j) w0[j] = pk_add(Kr0v[j], gr[j]);
#pragma unroll
      for (int j = 0; j < 5; ++j) w1[j] = pk_add(Kr1v[j], gr[j]);
      f32x2 a01 = pk_max(pk_max(w0[0], w0[1]), pk_max(w0[2], w0[3]));
      a01 = pk_max(a01, w0[4]);
      float mxa = fmaxf(a01.x, a01.y);
      f32x2 b01 = pk_max(pk_max(w1[0], w1[1]), pk_max(w1[2], w1[3]));
      b01 = pk_max(b01, w1[4]);
      float mxb2 = fmaxf(b01.x, b01.y);
      f32x2 mab = mk2(mxa, mxa);
      f32x2 mbb = mk2(mxb2, mxb2);
      f32x2 sx = pk_exp2(pk_sub(w0[0], mab));
      sx = pk_add(sx, pk_exp2(pk_sub(w0[1], mab)));
      sx = pk_add(sx, pk_exp2(pk_sub(w0[2], mab)));
      sx = pk_add(sx, pk_exp2(pk_sub(w0[3], mab)));
      sx = pk_add(sx, pk_exp2(pk_sub(w0[4], mab)));
      f32x2 sy = pk_exp2(pk_sub(w1[0], mbb));
      sy = pk_add(sy, pk_exp2(pk_sub(w1[1], mbb)));
      sy = pk_add(sy, pk_exp2(pk_sub(w1[2], mbb)));
      sy = pk_add(sy, pk_exp2(pk_sub(w1[3], mbb)));
      sy = pk_add(sy, pk_exp2(pk_sub(w1[4], mbb)));
      fr0 = lp2_r0 - mxa - LOG2F(sx.x + sx.y);
      fr1 = lp2_r1 - mxb2 - LOG2F(sy.x + sy.y);
      fLp[b] = fr0;
      fLp[10 + b] = fr1;   // b>=7 -> slots 17..19, never consumed
      CBAR();
    }

    // ---- stabilized kernels from (f2, g2) snapshot; rows re-paired (j, 10+j) ----
    f32x2 Kcs2[10];         // .y = 0 for j>=7 (pad rows 17..19)
    float P00, P01, Q0;
    f32x2 Krs01[10];
    {
      float4 F0 = *(const float4*)&fLp[0];
      float4 F1 = *(const float4*)&fLp[4];
      float4 F2 = *(const float4*)&fLp[8];
      float4 F3 = *(const float4*)&fLp[12];
      float f16v = fLp[16];
      float fs[K1];
      fs[0] = F0.x; fs[1] = F0.y; fs[2] = F0.z; fs[3] = F0.w;
      fs[4] = F1.x; fs[5] = F1.y; fs[6] = F1.z; fs[7] = F1.w;
      fs[8] = F2.x; fs[9] = F2.y; fs[10] = F2.z; fs[11] = F2.w;
      fs[12] = F3.x; fs[13] = F3.y; fs[14] = F3.z; fs[15] = F3.w;
      fs[16] = f16v;
      float qs[K1];
#pragma unroll
      for (int a = 0; a < K1; ++a) {
        float kcv = (a == 16) ? k16 : ((a & 1) ? Kc2v[a >> 1].y : Kc2v[a >> 1].x);
        qs[a] = kcv + fs[a];
      }
      float sigma = qs[0];
#pragma unroll
      for (int a = 1; a < K1; ++a) sigma = fmaxf(sigma, qs[a]);
#pragma unroll
      for (int j = 0; j < 10; ++j) {
        float kx = EXP2F(qs[j] - sigma);
        float ky = (j < 7) ? EXP2F(qs[10 + j] - sigma) : 0.f;
        Kcs2[j] = mk2(kx, ky);
      }
      Q0 = EXP2F(clamp120(LOGQ2 - sigma - g2));
      f32x2 a0[5], a1[5];
#pragma unroll
      for (int j = 0; j < 5; ++j) a0[j] = pk_add(Kr0v[j], gr[j]);
#pragma unroll
      for (int j = 0; j < 5; ++j) a1[j] = pk_add(Kr1v[j], gr[j]);
      f32x2 r0m = pk_max(pk_max(a0[0], a0[1]), pk_max(a0[2], a0[3]));
      r0m = pk_max(r0m, a0[4]);
      float rho0 = fmaxf(r0m.x, r0m.y);
      f32x2 r1m = pk_max(pk_max(a1[0], a1[1]), pk_max(a1[2], a1[3]));
      r1m = pk_max(r1m, a1[4]);
      float rho1 = fmaxf(r1m.x, r1m.y);
#pragma unroll
      for (int j = 0; j < 5; ++j) {
        Krs01[2 * j]     = mk2(EXP2F(a0[j].x - rho0), EXP2F(a1[j].x - rho1));
        Krs01[2 * j + 1] = mk2(EXP2F(a0[j].y - rho0), EXP2F(a1[j].y - rho1));
      }
      P00 = EXP2F(clamp120((lp2_r0 - rho0) - fr0));
      // pad rows (17..19): force u==0 so out-of-slot junk (possible NaN/Inf
      // from the 4-lane dummy slot) can never poison the real column sums.
      P01 = (b < 7) ? EXP2F(clamp120((lp2_r1 - rho1) - fr1)) : 0.f;
    }

    // ---- Sinkhorn iters 3..20: pure multiplicative, compact-w exchange ----
    // T5: raise wave priority for the LDS-round-trip-critical loop; waves in
    // the exp2-heavy log/stab phases (prio 0) are latency-tolerant.
    __builtin_amdgcn_s_setprio(1);
    float Slast, t0, t1;
    {  // peeled iter 3: u == 1
      f32x2 SA = pk_add(pk_add(Kcs2[0], Kcs2[1]), pk_add(Kcs2[2], Kcs2[3]));
      f32x2 SB = pk_add(pk_add(Kcs2[4], Kcs2[5]), pk_add(Kcs2[6], Kcs2[7]));
      f32x2 S2 = pk_add(pk_add(SA, SB), pk_add(Kcs2[8], Kcs2[9]));
      float S = fmaxf(S2.x + S2.y, TINYF);
      Slast = S;
      float wb = Q0 * RCPF(S);
      wLp[b] = wb;
      CBAR();
      float4 W0 = *(const float4*)&wLp[0];
      float4 W1 = *(const float4*)&wLp[4];
      f32x2 W2 = *(const f32x2*)&wLp[8];
      f32x2 tA = pk_mul(Krs01[0], mk2(W0.x, W0.x));
      tA = pk_fma(Krs01[1], mk2(W0.y, W0.y), tA);
      tA = pk_fma(Krs01[2], mk2(W0.z, W0.z), tA);
      tA = pk_fma(Krs01[3], mk2(W0.w, W0.w), tA);
      tA = pk_fma(Krs01[4], mk2(W1.x, W1.x), tA);
      f32x2 tB = pk_mul(Krs01[5], mk2(W1.y, W1.y));
      tB = pk_fma(Krs01[6], mk2(W1.z, W1.z), tB);
      tB = pk_fma(Krs01[7], mk2(W1.w, W1.w), tB);
      tB = pk_fma(Krs01[8], mk2(W2.x, W2.x), tB);
      tB = pk_fma(Krs01[9], mk2(W2.y, W2.y), tB);
      f32x2 t01 = pk_add(tA, tB);
      t0 = t01.x; t1 = t01.y;
    }
#pragma unroll 1
    for (int it = 0; it < 17; ++it) {   // iters 4..20
      float u0 = P00 * RCPF(fmaxf(t0, TINYF));
      float u1 = P01 * RCPF(fmaxf(t1, TINYF));
      *(f32x2*)&uLp[2 * b] = mk2(u0, u1);   // ONE b64 write
      CBAR();
      float4 U0 = *(const float4*)&uLp[0];    // (u0,u10, u1,u11)
      float4 U1 = *(const float4*)&uLp[4];
      float4 U2 = *(const float4*)&uLp[8];
      float4 U3 = *(const float4*)&uLp[12];
      float4 U4 = *(const float4*)&uLp[16];
      f32x2 SA = pk_mul(Kcs2[0], mk2(U0.x, U0.y));
      SA = pk_fma(Kcs2[1], mk2(U0.z, U0.w), SA);
      SA = pk_fma(Kcs2[2], mk2(U1.x, U1.y), SA);
      SA = pk_fma(Kcs2[3], mk2(U1.z, U1.w), SA);
      SA = pk_fma(Kcs2[4], mk2(U2.x, U2.y), SA);
      f32x2 SB = pk_mul(Kcs2[5], mk2(U2.z, U2.w));
      SB = pk_fma(Kcs2[6], mk2(U3.x, U3.y), SB);
      SB = pk_fma(Kcs2[7], mk2(U3.z, U3.w), SB);
      SB = pk_fma(Kcs2[8], mk2(U4.x, U4.y), SB);
      SB = pk_fma(Kcs2[9], mk2(U4.z, U4.w), SB);
      f32x2 S2 = pk_add(SA, SB);
      float S = fmaxf(S2.x + S2.y, TINYF);
      Slast = S;
      float wb = Q0 * RCPF(S);
      wLp[b] = wb;
      CBAR();
      float4 W0 = *(const float4*)&wLp[0];
      float4 W1 = *(const float4*)&wLp[4];
      f32x2 W2 = *(const f32x2*)&wLp[8];
      f32x2 tA = pk_mul(Krs01[0], mk2(W0.x, W0.x));
      tA = pk_fma(Krs01[1], mk2(W0.y, W0.y), tA);
      tA = pk_fma(Krs01[2], mk2(W0.z, W0.z), tA);
      tA = pk_fma(Krs01[3], mk2(W0.w, W0.w), tA);
      tA = pk_fma(Krs01[4], mk2(W1.x, W1.x), tA);
      f32x2 tB = pk_mul(Krs01[5], mk2(W1.y, W1.y));
      tB = pk_fma(Krs01[6], mk2(W1.z, W1.z), tB);
      tB = pk_fma(Krs01[7], mk2(W1.w, W1.w), tB);
      tB = pk_fma(Krs01[8], mk2(W2.x, W2.x), tB);
      tB = pk_fma(Krs01[9], mk2(W2.y, W2.y), tB);
      f32x2 t01 = pk_add(tA, tB);
      t0 = t01.x; t1 = t01.y;
    }

    // ---- final u + FW transport update: Tn = u * Kcs * (0.1/Slast), pairing matches ----
    {
      float u0 = P00 * RCPF(fmaxf(t0, TINYF));
      float u1 = P01 * RCPF(fmaxf(t1, TINYF));
      *(f32x2*)&uLp[2 * b] = mk2(u0, u1);
      CBAR();
      float4 U0 = *(const float4*)&uLp[0];
      float4 U1 = *(const float4*)&uLp[4];
      float4 U2 = *(const float4*)&uLp[8];
      float4 U3 = *(const float4*)&uLp[12];
      float4 U4 = *(const float4*)&uLp[16];
      const float gam = 2.f / ((float)k + 2.f);
      const float gs = gam * 0.1f * RCPF(Slast);
      const float om = 1.f - gam;
      const f32x2 omb = mk2(om, om);
      const f32x2 gsb = mk2(gs, gs);
      f32x2 uu[10];
      uu[0] = mk2(U0.x, U0.y); uu[1] = mk2(U0.z, U0.w);
      uu[2] = mk2(U1.x, U1.y); uu[3] = mk2(U1.z, U1.w);
      uu[4] = mk2(U2.x, U2.y); uu[5] = mk2(U2.z, U2.w);
      uu[6] = mk2(U3.x, U3.y); uu[7] = mk2(U3.z, U3.w);
      uu[8] = mk2(U4.x, U4.y); uu[9] = mk2(U4.z, U4.w);
#pragma unroll
      for (int j = 0; j < 10; ++j)
        Tp2[j] = pk_fma(omb, Tp2[j], pk_mul(gsb, pk_mul(Kcs2[j], uu[j])));
    }
    __builtin_amdgcn_s_setprio(0);
  }
}

extern "C" void kernel_launch(void* const* d_in, const int* in_sizes, int n_in,
                              void* d_out, int out_size, void* d_ws, size_t ws_size,
                              hipStream_t stream) {
  const float* x    = (const float*)d_in[0];
  const int*   ei   = (const int*)d_in[1];
  const float* tmpl = (const float*)d_in[2];
  const float* tf   = (const float*)d_in[3];
  float* out = (float*)d_out;

  int* cnt  = (int*)d_ws;
  int* ebuf = cnt + NNODE;
  int* nbrs = ebuf + (size_t)NNODE * CAP;
  int* kcnt = nbrs + (size_t)NNODE * KNB;
  int* Sg   = kcnt + NNODE;
  unsigned int* bits = (unsigned int*)(Sg + (size_t)NNODE * K1);
  float* Ag   = (float*)(bits + (size_t)NNODE * K1);
  float* dots = Ag + (size_t)NNODE * K1;
  float* nxv  = dots + (size_t)NNODE * (NT * TN);
  float* nF2  = nxv + NNODE;
  float* Bq   = nF2 + NT * TN;

  hipMemsetAsync(cnt, 0, NNODE * sizeof(int), stream);
  k_prep<<<625 + (NNODE + 15) / 16, 256, 0, stream>>>(ei, cnt, ebuf, x, tf, tmpl,
                                                      dots, nxv, nF2, Bq);
  k_select<<<(NNODE + 3) / 4, 256, 0, stream>>>(ei, cnt, ebuf, nbrs, kcnt, Sg);
  k_c1b<<<(NNODE * K1 + 255) / 256, 256, 0, stream>>>(nbrs, kcnt, Sg, bits, Ag);
  k_main<<<(NPAIR + 11) / 12, 128, 0, stream>>>(tmpl, kcnt, Sg, bits, Ag, dots, nxv, nF2, Bq, out);
}